// Round 1
// baseline (3286.732 us; speedup 1.0000x reference)
//
#include <hip/hip_runtime.h>

#define N_NODES 50000
#define N_EDGES 400000
#define DIN 128
#define HD 256
#define C2 512
#define CHUNK 50000
#define BN_EPS 1e-5f

// ---------------- utility kernels ----------------
__global__ void zero_i32(int* p, int n) {
    int i = blockIdx.x * blockDim.x + threadIdx.x;
    if (i < n) p[i] = 0;
}
__global__ void zero_f32(float* p, int n) {
    int i = blockIdx.x * blockDim.x + threadIdx.x;
    if (i < n) p[i] = 0.0f;
}

__global__ void count_deg(const int* __restrict__ dst, int* __restrict__ counts) {
    int e = blockIdx.x * blockDim.x + threadIdx.x;
    if (e < N_EDGES) atomicAdd(&counts[dst[e]], 1);
}

__global__ void isd_kernel(const int* __restrict__ counts, float* __restrict__ isd) {
    int i = blockIdx.x * blockDim.x + threadIdx.x;
    if (i < N_NODES) isd[i] = rsqrtf(1.0f + (float)counts[i]);
}

// single-block exclusive scan over counts -> offsets (N_NODES+1)
__global__ __launch_bounds__(256) void scan_kernel(const int* __restrict__ counts,
                                                   int* __restrict__ offsets) {
    __shared__ int sh[256];
    int t = threadIdx.x;
    int carry = 0;
    for (int base = 0; base < N_NODES; base += 256) {
        int i = base + t;
        int v = (i < N_NODES) ? counts[i] : 0;
        sh[t] = v;
        __syncthreads();
        for (int off = 1; off < 256; off <<= 1) {
            int add = (t >= off) ? sh[t - off] : 0;
            __syncthreads();
            sh[t] += add;
            __syncthreads();
        }
        if (i < N_NODES) offsets[i] = carry + sh[t] - v;
        carry += sh[255];
        __syncthreads();
    }
    if (t == 0) offsets[N_NODES] = carry;
}

__global__ void fill_csr(const int* __restrict__ src, const int* __restrict__ dst,
                         const float* __restrict__ isd, const int* __restrict__ offsets,
                         int* __restrict__ cursor, int* __restrict__ srcS,
                         float* __restrict__ normS) {
    int e = blockIdx.x * blockDim.x + threadIdx.x;
    if (e >= N_EDGES) return;
    int s = src[e], d = dst[e];
    int pos = offsets[d] + atomicAdd(&cursor[d], 1);
    srcS[pos] = s;
    normS[pos] = isd[s] * isd[d];
}

// ---------------- generic fp32 tiled GEMM: C = A(MxK) @ W(KxN) [+bias][relu] ----------------
#define BM 64
#define BNT 64
#define BK 16
__global__ __launch_bounds__(256) void gemm_bias(const float* __restrict__ A, int lda,
                                                 const float* __restrict__ W, int ldw,
                                                 float* __restrict__ C, int ldc,
                                                 const float* __restrict__ bias,
                                                 int M, int K, int relu) {
    __shared__ float As[BK][BM + 4];
    __shared__ float Ws[BK][BNT];
    int bm = blockIdx.x * BM;
    int bn = blockIdx.y * BNT;
    int tid = threadIdx.x;
    int tx = tid & 15, ty = tid >> 4;
    float acc[4][4] = {};
    for (int k0 = 0; k0 < K; k0 += BK) {
        {
            int row = tid >> 2;
            int kk = (tid & 3) * 4;
            float4 v = make_float4(0.f, 0.f, 0.f, 0.f);
            if (bm + row < M)
                v = *(const float4*)(A + (size_t)(bm + row) * lda + k0 + kk);
            As[kk + 0][row] = v.x; As[kk + 1][row] = v.y;
            As[kk + 2][row] = v.z; As[kk + 3][row] = v.w;
        }
        {
            int n = tid & 63;
            int kb = tid >> 6;
#pragma unroll
            for (int i = 0; i < 4; i++) {
                int k = kb + i * 4;
                Ws[k][n] = W[(size_t)(k0 + k) * ldw + bn + n];
            }
        }
        __syncthreads();
#pragma unroll
        for (int k = 0; k < BK; k++) {
            float a[4], b[4];
#pragma unroll
            for (int i = 0; i < 4; i++) a[i] = As[k][ty * 4 + i];
#pragma unroll
            for (int j = 0; j < 4; j++) b[j] = Ws[k][tx * 4 + j];
#pragma unroll
            for (int i = 0; i < 4; i++)
#pragma unroll
                for (int j = 0; j < 4; j++) acc[i][j] += a[i] * b[j];
        }
        __syncthreads();
    }
#pragma unroll
    for (int i = 0; i < 4; i++) {
        int row = bm + ty * 4 + i;
        if (row >= M) continue;
#pragma unroll
        for (int j = 0; j < 4; j++) {
            int col = bn + tx * 4 + j;
            float v = acc[i][j] + (bias ? bias[col] : 0.0f);
            if (relu) v = fmaxf(v, 0.0f);
            C[(size_t)row * ldc + col] = v;
        }
    }
}

// ---------------- GCN aggregation (CSR gather + self loop + bias) ----------------
// out[n][c] = sum_{e in-edges} hw[srcS][c]*normS + hw[n][c]*isd[n]^2 + bias[c]
__global__ __launch_bounds__(128) void aggregate(const float* __restrict__ hw,
                                                 const float* __restrict__ isd,
                                                 const int* __restrict__ offsets,
                                                 const int* __restrict__ srcS,
                                                 const float* __restrict__ normS,
                                                 const float* __restrict__ b1,
                                                 const float* __restrict__ b2,
                                                 float* __restrict__ out) {
    int n = blockIdx.x;
    int c = threadIdx.x * 4;  // 0..508
    float4 acc = make_float4(0.f, 0.f, 0.f, 0.f);
    int e0 = offsets[n], e1 = offsets[n + 1];
    for (int k = e0; k < e1; k++) {
        int s = srcS[k];
        float w = normS[k];
        float4 v = *(const float4*)(hw + (size_t)s * C2 + c);
        acc.x += v.x * w; acc.y += v.y * w; acc.z += v.z * w; acc.w += v.w * w;
    }
    float si = isd[n]; si *= si;
    float4 v = *(const float4*)(hw + (size_t)n * C2 + c);
    acc.x += v.x * si; acc.y += v.y * si; acc.z += v.z * si; acc.w += v.w * si;
    float4 bv = (c < 256) ? *(const float4*)(b1 + c) : *(const float4*)(b2 + (c - 256));
    acc.x += bv.x; acc.y += bv.y; acc.z += bv.z; acc.w += bv.w;
    *(float4*)(out + (size_t)n * C2 + c) = acc;
}

// ---------------- BatchNorm ----------------
__global__ __launch_bounds__(256) void bn_stats(const float* __restrict__ h,
                                                float* __restrict__ stats) {
    int t = threadIdx.x;
    int r0 = blockIdx.x * 64;
    int r1 = r0 + 64; if (r1 > N_NODES) r1 = N_NODES;
    float s1 = 0.f, q1 = 0.f, s2 = 0.f, q2 = 0.f;
    for (int r = r0; r < r1; r++) {
        float x = h[(size_t)r * C2 + t];
        float y = h[(size_t)r * C2 + 256 + t];
        s1 += x; q1 += x * x; s2 += y; q2 += y * y;
    }
    atomicAdd(&stats[t], s1);
    atomicAdd(&stats[256 + t], s2);
    atomicAdd(&stats[512 + t], q1);
    atomicAdd(&stats[768 + t], q2);
}

__global__ void bn_apply(float* __restrict__ h, const float* __restrict__ stats,
                         const float* __restrict__ g, const float* __restrict__ be) {
    int idx = blockIdx.x * blockDim.x + threadIdx.x;
    if (idx >= (int)(N_NODES * (size_t)C2)) return;
    int c = idx & 511;
    float m = stats[c] * (1.0f / N_NODES);
    float var = stats[512 + c] * (1.0f / N_NODES) - m * m;
    float sc = g[c & 255] * rsqrtf(var + BN_EPS);
    float x = h[idx];
    h[idx] = fmaxf((x - m) * sc + be[c & 255], 0.0f);
}

// final layer: apply BN+relu to both halves and write hc = h1+h2 (N x 256)
__global__ void bn_apply_final(const float* __restrict__ h, const float* __restrict__ stats,
                               const float* __restrict__ g, const float* __restrict__ be,
                               float* __restrict__ hc) {
    int idx = blockIdx.x * blockDim.x + threadIdx.x;
    if (idx >= N_NODES * HD) return;
    int n = idx >> 8;
    int c = idx & 255;
    float gm = g[c], bb = be[c];
    float m1 = stats[c] * (1.0f / N_NODES);
    float v1 = stats[512 + c] * (1.0f / N_NODES) - m1 * m1;
    float x1 = h[(size_t)n * C2 + c];
    float a1 = fmaxf((x1 - m1) * gm * rsqrtf(v1 + BN_EPS) + bb, 0.0f);
    int c2i = c + 256;
    float m2 = stats[c2i] * (1.0f / N_NODES);
    float v2 = stats[512 + c2i] * (1.0f / N_NODES) - m2 * m2;
    float x2 = h[(size_t)n * C2 + c2i];
    float a2 = fmaxf((x2 - m2) * gm * rsqrtf(v2 + BN_EPS) + bb, 0.0f);
    hc[idx] = a1 + a2;
}

// ---------------- edge MLP ----------------
// layer1: e1[e][c] = relu(P[src][c] + Q[dst][c] + sum_j ea[e][j]*Wc1e[j][c] + bc1[c])
__global__ __launch_bounds__(256) void edge_l1(const float* __restrict__ P,
                                               const float* __restrict__ Q,
                                               const int* __restrict__ src,
                                               const int* __restrict__ dst,
                                               const float* __restrict__ ea,
                                               const float* __restrict__ Wc1e,
                                               const float* __restrict__ bc1,
                                               float* __restrict__ e1out,
                                               int e_base, int count) {
    int el = blockIdx.x;
    if (el >= count) return;
    int e = e_base + el;
    int c = threadIdx.x;
    int s = src[e], d = dst[e];
    float v = P[(size_t)s * HD + c] + Q[(size_t)d * HD + c] + bc1[c];
#pragma unroll
    for (int j = 0; j < 8; j++) v += ea[(size_t)e * 8 + j] * Wc1e[j * HD + c];
    e1out[(size_t)el * HD + c] = fmaxf(v, 0.0f);
}

// final: out[e][0..1] = e2[el] (64) @ Wc5 (64x2) + bc5
__global__ void edge_out(const float* __restrict__ e2, const float* __restrict__ Wc5,
                         const float* __restrict__ bc5, float* __restrict__ out,
                         int e_base, int count) {
    int i = blockIdx.x * blockDim.x + threadIdx.x;
    if (i >= count) return;
    const float* r = e2 + (size_t)i * 64;
    float a0 = bc5[0], a1 = bc5[1];
#pragma unroll
    for (int k = 0; k < 64; k++) {
        float x = r[k];
        a0 += x * Wc5[k * 2 + 0];
        a1 += x * Wc5[k * 2 + 1];
    }
    out[(size_t)(e_base + i) * 2 + 0] = a0;
    out[(size_t)(e_base + i) * 2 + 1] = a1;
}

// ---------------- launch ----------------
extern "C" void kernel_launch(void* const* d_in, const int* in_sizes, int n_in,
                              void* d_out, int out_size, void* d_ws, size_t ws_size,
                              hipStream_t stream) {
    const float* x   = (const float*)d_in[0];
    const int*   ei  = (const int*)d_in[1];
    const float* ea  = (const float*)d_in[2];
    const float* W11 = (const float*)d_in[3];
    const float* b11 = (const float*)d_in[4];
    const float* W12 = (const float*)d_in[5];
    const float* b12 = (const float*)d_in[6];
    const float* W13 = (const float*)d_in[7];
    const float* b13 = (const float*)d_in[8];
    const float* W21 = (const float*)d_in[9];
    const float* b21 = (const float*)d_in[10];
    const float* W22 = (const float*)d_in[11];
    const float* b22 = (const float*)d_in[12];
    const float* W23 = (const float*)d_in[13];
    const float* b23 = (const float*)d_in[14];
    const float* g1  = (const float*)d_in[15];
    const float* be1 = (const float*)d_in[16];
    const float* g2  = (const float*)d_in[17];
    const float* be2 = (const float*)d_in[18];
    const float* g3  = (const float*)d_in[19];
    const float* be3 = (const float*)d_in[20];
    const float* Wc1 = (const float*)d_in[21];
    const float* bc1 = (const float*)d_in[22];
    const float* Wc2 = (const float*)d_in[23];
    const float* bc2 = (const float*)d_in[24];
    const float* Wc3 = (const float*)d_in[25];
    const float* bc3 = (const float*)d_in[26];
    const float* Wc4 = (const float*)d_in[27];
    const float* bc4 = (const float*)d_in[28];
    const float* Wc5 = (const float*)d_in[29];
    const float* bc5 = (const float*)d_in[30];

    const int* src = ei;
    const int* dst = ei + N_EDGES;

    // workspace layout (floats)
    float* ws = (float*)d_ws;
    size_t o = 0;
    float* isd = ws + o; o += N_NODES;           o = (o + 255) & ~(size_t)255;
    float* normS = ws + o; o += N_EDGES;         o = (o + 255) & ~(size_t)255;
    int* srcS = (int*)(ws + o); o += N_EDGES;    o = (o + 255) & ~(size_t)255;
    int* counts = (int*)(ws + o); o += N_NODES + 1; o = (o + 255) & ~(size_t)255;
    int* offsets = (int*)(ws + o); o += N_NODES + 1; o = (o + 255) & ~(size_t)255;
    float* stats = ws + o; o += 1024;            o = (o + 255) & ~(size_t)255;
    float* bufA = ws + o; o += (size_t)N_NODES * C2;
    float* bufB = ws + o; o += (size_t)N_NODES * C2;
    (void)ws_size;

    float* out = (float*)d_out;

    auto gemm = [&](const float* A, int lda, const float* W, int ldw, float* C, int ldc,
                    const float* bias, int M, int K, int Nc, int relu) {
        dim3 g((M + BM - 1) / BM, Nc / BNT);
        gemm_bias<<<g, 256, 0, stream>>>(A, lda, W, ldw, C, ldc, bias, M, K, relu);
    };

    // ---- degree + CSR build ----
    zero_i32<<<(N_NODES + 256) / 256, 256, 0, stream>>>(counts, N_NODES + 1);
    count_deg<<<(N_EDGES + 255) / 256, 256, 0, stream>>>(dst, counts);
    isd_kernel<<<(N_NODES + 255) / 256, 256, 0, stream>>>(counts, isd);
    scan_kernel<<<1, 256, 0, stream>>>(counts, offsets);
    zero_i32<<<(N_NODES + 255) / 256, 256, 0, stream>>>(counts, N_NODES);
    fill_csr<<<(N_EDGES + 255) / 256, 256, 0, stream>>>(src, dst, isd, offsets, counts,
                                                        srcS, normS);

    // ---- 3 GCN layers (both branches fused as 512 channels) ----
    const float* Wa[3] = {W11, W12, W13};
    const float* Wb[3] = {W21, W22, W23};
    const float* ba[3] = {b11, b12, b13};
    const float* bb[3] = {b21, b22, b23};
    const float* gs[3] = {g1, g2, g3};
    const float* bes[3] = {be1, be2, be3};

    for (int l = 0; l < 3; l++) {
        if (l == 0) {
            gemm(x, DIN, Wa[0], HD, bufB, C2, nullptr, N_NODES, DIN, HD, 0);
            gemm(x, DIN, Wb[0], HD, bufB + HD, C2, nullptr, N_NODES, DIN, HD, 0);
        } else {
            gemm(bufA, C2, Wa[l], HD, bufB, C2, nullptr, N_NODES, HD, HD, 0);
            gemm(bufA + HD, C2, Wb[l], HD, bufB + HD, C2, nullptr, N_NODES, HD, HD, 0);
        }
        aggregate<<<N_NODES, 128, 0, stream>>>(bufB, isd, offsets, srcS, normS,
                                               ba[l], bb[l], bufA);
        zero_f32<<<4, 256, 0, stream>>>(stats, 1024);
        bn_stats<<<(N_NODES + 63) / 64, 256, 0, stream>>>(bufA, stats);
        if (l < 2) {
            size_t tot = (size_t)N_NODES * C2;
            bn_apply<<<(int)((tot + 255) / 256), 256, 0, stream>>>(bufA, stats, gs[l], bes[l]);
        } else {
            int tot = N_NODES * HD;
            bn_apply_final<<<(tot + 255) / 256, 256, 0, stream>>>(bufA, stats, gs[l], bes[l],
                                                                  bufB);
        }
    }

    // ---- P = hc @ Wc1[0:256], Q = hc @ Wc1[256:512] ----
    float* P = bufA;
    float* Q = bufA + (size_t)N_NODES * HD;
    gemm(bufB, HD, Wc1, HD, P, HD, nullptr, N_NODES, HD, HD, 0);
    gemm(bufB, HD, Wc1 + 256 * HD, HD, Q, HD, nullptr, N_NODES, HD, HD, 0);

    // ---- edge MLP in chunks ----
    float* e1 = bufB;
    float* e2 = bufB + (size_t)CHUNK * HD;
    for (int c0 = 0; c0 < N_EDGES; c0 += CHUNK) {
        int cnt = (N_EDGES - c0 < CHUNK) ? (N_EDGES - c0) : CHUNK;
        edge_l1<<<cnt, 256, 0, stream>>>(P, Q, src, dst, ea, Wc1 + 512 * HD, bc1, e1, c0, cnt);
        gemm(e1, HD, Wc2, HD, e2, HD, bc2, cnt, HD, HD, 1);
        gemm(e2, HD, Wc3, 128, e1, 128, bc3, cnt, HD, 128, 1);
        gemm(e1, 128, Wc4, 64, e2, 64, bc4, cnt, 128, 64, 1);
        edge_out<<<(cnt + 255) / 256, 256, 0, stream>>>(e2, Wc5, bc5, out, c0, cnt);
    }
}

// Round 2
// 1282.116 us; speedup vs baseline: 2.5635x; 2.5635x over previous
//
#include <hip/hip_runtime.h>

#define N_NODES 50000
#define N_EDGES 400000
#define CHUNK   100000
#define NB_SCAN 196      // ceil(50000/256)
#define BN_EPS  1e-5f

typedef __attribute__((ext_vector_type(8))) short s16x8;
typedef __attribute__((ext_vector_type(4))) float f32x4;

__device__ __forceinline__ unsigned short f2bf(float x) {
    unsigned u = __float_as_uint(x);
    return (unsigned short)((u + 0x7fffu + ((u >> 16) & 1u)) >> 16);
}
__device__ __forceinline__ float bf2f(unsigned short b) {
    return __uint_as_float(((unsigned)b) << 16);
}

// ---------------- utility ----------------
__global__ void zero_i32(int* p, int n) {
    int i = blockIdx.x * blockDim.x + threadIdx.x;
    if (i < n) p[i] = 0;
}
__global__ void zero_f32(float* p, int n) {
    int i = blockIdx.x * blockDim.x + threadIdx.x;
    if (i < n) p[i] = 0.0f;
}
__global__ void count_deg(const int* __restrict__ dst, int* __restrict__ counts) {
    int e = blockIdx.x * blockDim.x + threadIdx.x;
    if (e < N_EDGES) atomicAdd(&counts[dst[e]], 1);
}
__global__ void isd_kernel(const int* __restrict__ counts, float* __restrict__ isd) {
    int i = blockIdx.x * blockDim.x + threadIdx.x;
    if (i < N_NODES) isd[i] = rsqrtf(1.0f + (float)counts[i]);
}

// ---------------- 3-phase scan ----------------
__global__ __launch_bounds__(256) void scan_reduce(const int* __restrict__ counts,
                                                   int* __restrict__ bsum) {
    __shared__ int sh[256];
    int t = threadIdx.x, b = blockIdx.x;
    int i = b * 256 + t;
    sh[t] = (i < N_NODES) ? counts[i] : 0;
    __syncthreads();
    for (int o = 128; o > 0; o >>= 1) {
        if (t < o) sh[t] += sh[t + o];
        __syncthreads();
    }
    if (t == 0) bsum[b] = sh[0];
}
__global__ __launch_bounds__(256) void scan_tops(const int* __restrict__ bsum,
                                                 int* __restrict__ boff, int nb,
                                                 int* __restrict__ total_out) {
    __shared__ int sh[256];
    int t = threadIdx.x;
    int v = (t < nb) ? bsum[t] : 0;
    sh[t] = v;
    __syncthreads();
    for (int o = 1; o < 256; o <<= 1) {
        int a = (t >= o) ? sh[t - o] : 0;
        __syncthreads();
        sh[t] += a;
        __syncthreads();
    }
    if (t < nb) boff[t] = sh[t] - v;
    if (t == 255) *total_out = sh[255];
}
__global__ __launch_bounds__(256) void scan_final(const int* __restrict__ counts,
                                                  const int* __restrict__ boff,
                                                  int* __restrict__ offsets) {
    __shared__ int sh[256];
    int t = threadIdx.x, b = blockIdx.x;
    int i = b * 256 + t;
    int v = (i < N_NODES) ? counts[i] : 0;
    sh[t] = v;
    __syncthreads();
    for (int o = 1; o < 256; o <<= 1) {
        int a = (t >= o) ? sh[t - o] : 0;
        __syncthreads();
        sh[t] += a;
        __syncthreads();
    }
    if (i < N_NODES) offsets[i] = boff[b] + sh[t] - v;
}

__global__ void fill_csr(const int* __restrict__ src, const int* __restrict__ dst,
                         const float* __restrict__ isd, const int* __restrict__ offsets,
                         int* __restrict__ cursor, int* __restrict__ srcS,
                         float* __restrict__ normS) {
    int e = blockIdx.x * blockDim.x + threadIdx.x;
    if (e >= N_EDGES) return;
    int s = src[e], d = dst[e];
    int pos = offsets[d] + atomicAdd(&cursor[d], 1);
    srcS[pos] = s;
    normS[pos] = isd[s] * isd[d];
}

// ---------------- conversions ----------------
__global__ void conv_f32_bf16(const float* __restrict__ in, unsigned short* __restrict__ out,
                              int n4) {
    int i = blockIdx.x * blockDim.x + threadIdx.x;
    if (i >= n4) return;
    float4 v = ((const float4*)in)[i];
    unsigned short o0 = f2bf(v.x), o1 = f2bf(v.y), o2 = f2bf(v.z), o3 = f2bf(v.w);
    unsigned r0 = ((unsigned)o1 << 16) | o0;
    unsigned r1 = ((unsigned)o3 << 16) | o2;
    ((uint2*)out)[i] = make_uint2(r0, r1);
}

// W [K][Nout] fp32 -> Wt [Nout][K] bf16
__global__ void transp_conv(const float* __restrict__ W, unsigned short* __restrict__ Wt,
                            int K, int Nout) {
    int idx = blockIdx.x * blockDim.x + threadIdx.x;
    if (idx >= K * Nout) return;
    int k = idx / Nout, n = idx % Nout;
    Wt[(size_t)n * K + k] = f2bf(W[idx]);
}

// ---------------- bf16 MFMA GEMM ----------------
// C[M][Nout] = A[M][K](bf16, lda) @ Wt[Nout][K](bf16)^T  [+bias][relu]
// 4 waves; BN_T=128: 2x2 waves of 64x64; BN_T=64: 4x1 waves of 32x64.
template <int BN_T, int OUT_BF16, int RELU, int BIAS>
__global__ __launch_bounds__(256) void gemm_mfma(const unsigned short* __restrict__ A, int lda,
                                                 const unsigned short* __restrict__ Wt,
                                                 const float* __restrict__ bias,
                                                 void* __restrict__ Cout, int ldc,
                                                 int M, int K) {
    constexpr int BM = 128;
    constexpr int MI = (BN_T == 128) ? 4 : 2;
    constexpr int NI = 4;
    __shared__ __align__(16) short As[BM * 32];
    __shared__ __align__(16) short Bs[BN_T * 32];

    int tid = threadIdx.x;
    int l = tid & 63;
    int wid = tid >> 6;
    int wrow = (BN_T == 128) ? (wid >> 1) * 64 : wid * 32;
    int wcol = (BN_T == 128) ? (wid & 1) * 64 : 0;

    int bm = blockIdx.x * BM;
    int bn = blockIdx.y * BN_T;

    f32x4 acc[MI][NI] = {};
    int swz = ((l >> 4) ^ (l & 3)) << 3;  // bf16-element offset within a 32-elem row

    for (int k0 = 0; k0 < K; k0 += 32) {
        // stage A tile: 128 rows x 32 bf16, 16B-granule XOR swizzle
#pragma unroll
        for (int i = 0; i < 2; i++) {
            int idx = i * 256 + tid;
            int row = idx >> 2, g = idx & 3;
            int rc = bm + row;
            if (rc >= M) rc = M - 1;
            int di = row * 32 + ((g ^ (row & 3)) << 3);
            *(int4*)(&As[di]) = *(const int4*)(&A[(size_t)rc * lda + k0 + g * 8]);
        }
        // stage B tile: BN_T rows x 32 bf16
#pragma unroll
        for (int i = 0; i < BN_T / 64; i++) {
            int idx = i * 256 + tid;
            int row = idx >> 2, g = idx & 3;
            int di = row * 32 + ((g ^ (row & 3)) << 3);
            *(int4*)(&Bs[di]) = *(const int4*)(&Wt[(size_t)(bn + row) * K + k0 + g * 8]);
        }
        __syncthreads();
        s16x8 af[MI], bfr[NI];
#pragma unroll
        for (int mi = 0; mi < MI; mi++) {
            int r = wrow + mi * 16 + (l & 15);
            af[mi] = *(const s16x8*)(&As[r * 32 + swz]);
        }
#pragma unroll
        for (int ni = 0; ni < NI; ni++) {
            int r = wcol + ni * 16 + (l & 15);
            bfr[ni] = *(const s16x8*)(&Bs[r * 32 + swz]);
        }
#pragma unroll
        for (int mi = 0; mi < MI; mi++)
#pragma unroll
            for (int ni = 0; ni < NI; ni++)
                acc[mi][ni] = __builtin_amdgcn_mfma_f32_16x16x32_bf16(af[mi], bfr[ni],
                                                                      acc[mi][ni], 0, 0, 0);
        __syncthreads();
    }
    // epilogue: D lane layout col=l&15, row=(l>>4)*4+r
#pragma unroll
    for (int mi = 0; mi < MI; mi++) {
#pragma unroll
        for (int ni = 0; ni < NI; ni++) {
            int colB = bn + wcol + ni * 16 + (l & 15);
            float bv = BIAS ? bias[colB] : 0.0f;
#pragma unroll
            for (int r = 0; r < 4; r++) {
                int row = bm + wrow + mi * 16 + (l >> 4) * 4 + r;
                if (row < M) {
                    float v = acc[mi][ni][r] + bv;
                    if (RELU) v = fmaxf(v, 0.0f);
                    if (OUT_BF16)
                        ((unsigned short*)Cout)[(size_t)row * ldc + colB] = f2bf(v);
                    else
                        ((float*)Cout)[(size_t)row * ldc + colB] = v;
                }
            }
        }
    }
}

// ---------------- GCN aggregation: wave per node, bf16 gathers ----------------
__global__ __launch_bounds__(256) void aggregate(const unsigned short* __restrict__ hwb,
                                                 const float* __restrict__ isd,
                                                 const int* __restrict__ offsets,
                                                 const int* __restrict__ srcS,
                                                 const float* __restrict__ normS,
                                                 const float* __restrict__ b1,
                                                 const float* __restrict__ b2,
                                                 float* __restrict__ outA) {
    int wid = threadIdx.x >> 6;
    int l = threadIdx.x & 63;
    int n = blockIdx.x * 4 + wid;
    if (n >= N_NODES) return;
    int c0 = l * 8;
    float acc[8] = {};
    int e0 = offsets[n], e1 = offsets[n + 1];
    for (int k = e0; k < e1; k++) {
        int s = srcS[k];
        float w = normS[k];
        union { int4 v; unsigned short u[8]; } U;
        U.v = *(const int4*)(&hwb[(size_t)s * 512 + c0]);
#pragma unroll
        for (int j = 0; j < 8; j++) acc[j] += w * bf2f(U.u[j]);
    }
    float si = isd[n]; si *= si;
    {
        union { int4 v; unsigned short u[8]; } U;
        U.v = *(const int4*)(&hwb[(size_t)n * 512 + c0]);
#pragma unroll
        for (int j = 0; j < 8; j++) acc[j] += si * bf2f(U.u[j]);
    }
    const float* bp = (c0 < 256) ? (b1 + c0) : (b2 + (c0 - 256));
#pragma unroll
    for (int j = 0; j < 8; j++) acc[j] += bp[j];
    float4 o0 = make_float4(acc[0], acc[1], acc[2], acc[3]);
    float4 o1 = make_float4(acc[4], acc[5], acc[6], acc[7]);
    *(float4*)(&outA[(size_t)n * 512 + c0]) = o0;
    *(float4*)(&outA[(size_t)n * 512 + c0 + 4]) = o1;
}

// ---------------- BatchNorm ----------------
__global__ __launch_bounds__(256) void bn_stats(const float* __restrict__ h,
                                                float* __restrict__ stats) {
    int t = threadIdx.x;
    int r0 = blockIdx.x * 64;
    int r1 = r0 + 64; if (r1 > N_NODES) r1 = N_NODES;
    float s1 = 0.f, q1 = 0.f, s2 = 0.f, q2 = 0.f;
    for (int r = r0; r < r1; r++) {
        float x = h[(size_t)r * 512 + t];
        float y = h[(size_t)r * 512 + 256 + t];
        s1 += x; q1 += x * x; s2 += y; q2 += y * y;
    }
    atomicAdd(&stats[t], s1);
    atomicAdd(&stats[256 + t], s2);
    atomicAdd(&stats[512 + t], q1);
    atomicAdd(&stats[768 + t], q2);
}

// bufA fp32 -> hb bf16 (both 512-wide), BN + relu
__global__ __launch_bounds__(256) void bn_apply(const float* __restrict__ h,
                                                const float* __restrict__ stats,
                                                const float* __restrict__ g,
                                                const float* __restrict__ be,
                                                unsigned short* __restrict__ out) {
    int i4 = blockIdx.x * blockDim.x + threadIdx.x;
    if (i4 >= N_NODES * 512 / 4) return;
    int c4 = (i4 & 127) * 4;
    float4 x = *(const float4*)(&h[(size_t)i4 * 4]);
    float xs[4] = {x.x, x.y, x.z, x.w};
    unsigned short os[4];
#pragma unroll
    for (int j = 0; j < 4; j++) {
        int c = c4 + j;
        float m = stats[c] * (1.0f / N_NODES);
        float var = stats[512 + c] * (1.0f / N_NODES) - m * m;
        float sc = g[c & 255] * rsqrtf(var + BN_EPS);
        os[j] = f2bf(fmaxf((xs[j] - m) * sc + be[c & 255], 0.0f));
    }
    unsigned r0 = ((unsigned)os[1] << 16) | os[0];
    unsigned r1 = ((unsigned)os[3] << 16) | os[2];
    *(uint2*)(&out[(size_t)i4 * 4]) = make_uint2(r0, r1);
}

// final: BN+relu both halves, hc = h1+h2 (bf16, 256-wide)
__global__ __launch_bounds__(256) void bn_apply_final(const float* __restrict__ h,
                                                      const float* __restrict__ stats,
                                                      const float* __restrict__ g,
                                                      const float* __restrict__ be,
                                                      unsigned short* __restrict__ hc) {
    int i4 = blockIdx.x * blockDim.x + threadIdx.x;
    if (i4 >= N_NODES * 256 / 4) return;
    int n = i4 >> 6;
    int c4 = (i4 & 63) * 4;
    float4 x1 = *(const float4*)(&h[(size_t)n * 512 + c4]);
    float4 x2 = *(const float4*)(&h[(size_t)n * 512 + 256 + c4]);
    float a1[4] = {x1.x, x1.y, x1.z, x1.w};
    float a2[4] = {x2.x, x2.y, x2.z, x2.w};
    unsigned short os[4];
#pragma unroll
    for (int j = 0; j < 4; j++) {
        int c = c4 + j;
        float gm = g[c], bb = be[c];
        float m1 = stats[c] * (1.0f / N_NODES);
        float v1 = stats[512 + c] * (1.0f / N_NODES) - m1 * m1;
        float r1v = fmaxf((a1[j] - m1) * gm * rsqrtf(v1 + BN_EPS) + bb, 0.0f);
        int cc = c + 256;
        float m2 = stats[cc] * (1.0f / N_NODES);
        float v2 = stats[512 + cc] * (1.0f / N_NODES) - m2 * m2;
        float r2v = fmaxf((a2[j] - m2) * gm * rsqrtf(v2 + BN_EPS) + bb, 0.0f);
        os[j] = f2bf(r1v + r2v);
    }
    unsigned r0 = ((unsigned)os[1] << 16) | os[0];
    unsigned r1 = ((unsigned)os[3] << 16) | os[2];
    *(uint2*)(&hc[(size_t)i4 * 4]) = make_uint2(r0, r1);
}

// ---------------- edge MLP layer 1: wave per edge ----------------
// e1[el][c] = relu(PQ[s][c] + PQ[d][256+c] + ea[e]@Wc1e[:, c] + bc1[c]), bf16 out
__global__ __launch_bounds__(256) void edge_l1(const unsigned short* __restrict__ PQ,
                                               const int* __restrict__ src,
                                               const int* __restrict__ dst,
                                               const float* __restrict__ ea,
                                               const float* __restrict__ Wc1e,
                                               const float* __restrict__ bc1,
                                               unsigned short* __restrict__ e1out,
                                               int e_base, int count) {
    int wid = threadIdx.x >> 6, l = threadIdx.x & 63;
    int el = blockIdx.x * 4 + wid;
    if (el >= count) return;
    int e = e_base + el;
    int s = src[e], d = dst[e];
    int c0 = l * 4;
    union { int2 v; unsigned short u[4]; } Pu, Qu;
    Pu.v = *(const int2*)(&PQ[(size_t)s * 512 + c0]);
    Qu.v = *(const int2*)(&PQ[(size_t)d * 512 + 256 + c0]);
    float v[4];
#pragma unroll
    for (int j = 0; j < 4; j++) v[j] = bf2f(Pu.u[j]) + bf2f(Qu.u[j]) + bc1[c0 + j];
#pragma unroll
    for (int jj = 0; jj < 8; jj++) {
        float av = ea[(size_t)e * 8 + jj];
        float4 w = *(const float4*)(&Wc1e[jj * 256 + c0]);
        v[0] += av * w.x; v[1] += av * w.y; v[2] += av * w.z; v[3] += av * w.w;
    }
    unsigned short os[4];
#pragma unroll
    for (int j = 0; j < 4; j++) os[j] = f2bf(fmaxf(v[j], 0.0f));
    unsigned r0 = ((unsigned)os[1] << 16) | os[0];
    unsigned r1 = ((unsigned)os[3] << 16) | os[2];
    *(uint2*)(&e1out[(size_t)el * 256 + c0]) = make_uint2(r0, r1);
}

// ---------------- final 64->2 ----------------
__global__ void edge_out(const unsigned short* __restrict__ e4,
                         const float* __restrict__ Wc5, const float* __restrict__ bc5,
                         float* __restrict__ out, int e_base, int count) {
    int i = blockIdx.x * blockDim.x + threadIdx.x;
    if (i >= count) return;
    float a0 = bc5[0], a1 = bc5[1];
    for (int k8 = 0; k8 < 8; k8++) {
        union { int4 v; unsigned short u[8]; } U;
        U.v = *(const int4*)(&e4[(size_t)i * 64 + k8 * 8]);
#pragma unroll
        for (int j = 0; j < 8; j++) {
            float x = bf2f(U.u[j]);
            a0 += x * Wc5[(k8 * 8 + j) * 2 + 0];
            a1 += x * Wc5[(k8 * 8 + j) * 2 + 1];
        }
    }
    out[(size_t)(e_base + i) * 2 + 0] = a0;
    out[(size_t)(e_base + i) * 2 + 1] = a1;
}

// ---------------- launch ----------------
extern "C" void kernel_launch(void* const* d_in, const int* in_sizes, int n_in,
                              void* d_out, int out_size, void* d_ws, size_t ws_size,
                              hipStream_t stream) {
    const float* x   = (const float*)d_in[0];
    const int*   ei  = (const int*)d_in[1];
    const float* ea  = (const float*)d_in[2];
    const float* W11 = (const float*)d_in[3];
    const float* b11 = (const float*)d_in[4];
    const float* W12 = (const float*)d_in[5];
    const float* b12 = (const float*)d_in[6];
    const float* W13 = (const float*)d_in[7];
    const float* b13 = (const float*)d_in[8];
    const float* W21 = (const float*)d_in[9];
    const float* b21 = (const float*)d_in[10];
    const float* W22 = (const float*)d_in[11];
    const float* b22 = (const float*)d_in[12];
    const float* W23 = (const float*)d_in[13];
    const float* b23 = (const float*)d_in[14];
    const float* g1  = (const float*)d_in[15];
    const float* be1 = (const float*)d_in[16];
    const float* g2  = (const float*)d_in[17];
    const float* be2 = (const float*)d_in[18];
    const float* g3  = (const float*)d_in[19];
    const float* be3 = (const float*)d_in[20];
    const float* Wc1 = (const float*)d_in[21];
    const float* bc1 = (const float*)d_in[22];
    const float* Wc2 = (const float*)d_in[23];
    const float* bc2 = (const float*)d_in[24];
    const float* Wc3 = (const float*)d_in[25];
    const float* bc3 = (const float*)d_in[26];
    const float* Wc4 = (const float*)d_in[27];
    const float* bc4 = (const float*)d_in[28];
    const float* Wc5 = (const float*)d_in[29];
    const float* bc5 = (const float*)d_in[30];

    const int* src = ei;
    const int* dst = ei + N_EDGES;
    float* out = (float*)d_out;

    // ---- workspace carve ----
    char* w = (char*)d_ws;
    auto alloc = [&](size_t bytes) {
        char* p = w;
        w += (bytes + 255) & ~(size_t)255;
        return p;
    };
    float* isd     = (float*)alloc(N_NODES * 4);
    float* normS   = (float*)alloc(N_EDGES * 4);
    int*   srcS    = (int*)alloc(N_EDGES * 4);
    int*   counts  = (int*)alloc((N_NODES + 4) * 4);
    int*   offsets = (int*)alloc((N_NODES + 4) * 4);
    int*   bsum    = (int*)alloc(256 * 4);
    int*   boff    = (int*)alloc(256 * 4);
    float* stats   = (float*)alloc(1024 * 4);
    unsigned short* W11t = (unsigned short*)alloc(256 * 128 * 2);
    unsigned short* W21t = (unsigned short*)alloc(256 * 128 * 2);
    unsigned short* W12t = (unsigned short*)alloc(256 * 256 * 2);
    unsigned short* W22t = (unsigned short*)alloc(256 * 256 * 2);
    unsigned short* W13t = (unsigned short*)alloc(256 * 256 * 2);
    unsigned short* W23t = (unsigned short*)alloc(256 * 256 * 2);
    unsigned short* WPQt = (unsigned short*)alloc(512 * 256 * 2);
    unsigned short* Wc2t = (unsigned short*)alloc(256 * 256 * 2);
    unsigned short* Wc3t = (unsigned short*)alloc(128 * 256 * 2);
    unsigned short* Wc4t = (unsigned short*)alloc(64 * 128 * 2);
    unsigned short* xb   = (unsigned short*)alloc((size_t)N_NODES * 128 * 2);
    unsigned short* hb   = (unsigned short*)alloc((size_t)N_NODES * 512 * 2);
    unsigned short* hwb  = (unsigned short*)alloc((size_t)N_NODES * 512 * 2);
    float*          bufA = (float*)alloc((size_t)N_NODES * 512 * 4);
    unsigned short* hc   = (unsigned short*)alloc((size_t)N_NODES * 256 * 2);
    (void)ws_size;

    // edge-phase arena aliases bufA (dead by then)
    unsigned short* e1 = (unsigned short*)bufA;
    unsigned short* e2 = e1 + (size_t)CHUNK * 256;
    unsigned short* e3 = e1;  // reuse, e1 dead after Wc2 gemm
    unsigned short* e4 = e2;  // reuse, e2 dead after Wc3 gemm

    // ---- CSR build ----
    zero_i32<<<(N_NODES + 256) / 256, 256, 0, stream>>>(counts, N_NODES + 1);
    count_deg<<<(N_EDGES + 255) / 256, 256, 0, stream>>>(dst, counts);
    isd_kernel<<<(N_NODES + 255) / 256, 256, 0, stream>>>(counts, isd);
    scan_reduce<<<NB_SCAN, 256, 0, stream>>>(counts, bsum);
    scan_tops<<<1, 256, 0, stream>>>(bsum, boff, NB_SCAN, offsets + N_NODES);
    scan_final<<<NB_SCAN, 256, 0, stream>>>(counts, boff, offsets);
    zero_i32<<<(N_NODES + 255) / 256, 256, 0, stream>>>(counts, N_NODES);
    fill_csr<<<(N_EDGES + 255) / 256, 256, 0, stream>>>(src, dst, isd, offsets, counts,
                                                        srcS, normS);

    // ---- preconvert: x -> bf16, weights -> transposed bf16 ----
    conv_f32_bf16<<<(N_NODES * 128 / 4 + 255) / 256, 256, 0, stream>>>(x, xb,
                                                                        N_NODES * 128 / 4);
    auto tr = [&](const float* W, unsigned short* Wt, int K, int Nout) {
        transp_conv<<<(K * Nout + 255) / 256, 256, 0, stream>>>(W, Wt, K, Nout);
    };
    tr(W11, W11t, 128, 256); tr(W21, W21t, 128, 256);
    tr(W12, W12t, 256, 256); tr(W22, W22t, 256, 256);
    tr(W13, W13t, 256, 256); tr(W23, W23t, 256, 256);
    tr(Wc1, WPQt, 256, 256);                    // P-part rows 0..255
    tr(Wc1 + 256 * 256, WPQt + 256 * 256, 256, 256);  // Q-part rows 256..511
    tr(Wc2, Wc2t, 256, 256);
    tr(Wc3, Wc3t, 256, 128);
    tr(Wc4, Wc4t, 128, 64);

    // ---- 3 GCN layers ----
    const unsigned short* Wat[3] = {W11t, W12t, W13t};
    const unsigned short* Wbt[3] = {W21t, W22t, W23t};
    const float* ba[3] = {b11, b12, b13};
    const float* bb[3] = {b21, b22, b23};
    const float* gs[3] = {g1, g2, g3};
    const float* bes[3] = {be1, be2, be3};

    int gx_n = (N_NODES + 127) / 128;  // 391
    for (int l = 0; l < 3; l++) {
        if (l == 0) {
            gemm_mfma<128, 1, 0, 0><<<dim3(gx_n, 2), 256, 0, stream>>>(
                xb, 128, Wat[0], nullptr, hwb, 512, N_NODES, 128);
            gemm_mfma<128, 1, 0, 0><<<dim3(gx_n, 2), 256, 0, stream>>>(
                xb, 128, Wbt[0], nullptr, hwb + 256, 512, N_NODES, 128);
        } else {
            gemm_mfma<128, 1, 0, 0><<<dim3(gx_n, 2), 256, 0, stream>>>(
                hb, 512, Wat[l], nullptr, hwb, 512, N_NODES, 256);
            gemm_mfma<128, 1, 0, 0><<<dim3(gx_n, 2), 256, 0, stream>>>(
                hb + 256, 512, Wbt[l], nullptr, hwb + 256, 512, N_NODES, 256);
        }
        aggregate<<<(N_NODES + 3) / 4, 256, 0, stream>>>(hwb, isd, offsets, srcS, normS,
                                                         ba[l], bb[l], bufA);
        zero_f32<<<4, 256, 0, stream>>>(stats, 1024);
        bn_stats<<<(N_NODES + 63) / 64, 256, 0, stream>>>(bufA, stats);
        if (l < 2) {
            bn_apply<<<(N_NODES * 512 / 4 + 255) / 256, 256, 0, stream>>>(bufA, stats,
                                                                          gs[l], bes[l], hb);
        } else {
            bn_apply_final<<<(N_NODES * 256 / 4 + 255) / 256, 256, 0, stream>>>(
                bufA, stats, gs[l], bes[l], hc);
        }
    }

    // ---- PQ = hc @ [Wc1_P | Wc1_Q]  -> hwb [N][512] bf16 ----
    gemm_mfma<128, 1, 0, 0><<<dim3(gx_n, 4), 256, 0, stream>>>(hc, 256, WPQt, nullptr,
                                                               hwb, 512, N_NODES, 256);

    // ---- edge MLP in chunks of 100K ----
    int gx_e = (CHUNK + 127) / 128;  // 782
    for (int c0 = 0; c0 < N_EDGES; c0 += CHUNK) {
        int cnt = CHUNK;
        edge_l1<<<(cnt + 3) / 4, 256, 0, stream>>>(hwb, src, dst, ea, Wc1 + 512 * 256, bc1,
                                                   e1, c0, cnt);
        gemm_mfma<128, 1, 1, 1><<<dim3(gx_e, 2), 256, 0, stream>>>(e1, 256, Wc2t, bc2,
                                                                   e2, 256, cnt, 256);
        gemm_mfma<128, 1, 1, 1><<<dim3(gx_e, 1), 256, 0, stream>>>(e2, 256, Wc3t, bc3,
                                                                   e3, 128, cnt, 256);
        gemm_mfma<64, 1, 1, 1><<<dim3(gx_e, 1), 256, 0, stream>>>(e3, 128, Wc4t, bc4,
                                                                  e4, 64, cnt, 128);
        edge_out<<<(cnt + 255) / 256, 256, 0, stream>>>(e4, Wc5, bc5, out, c0, cnt);
    }
}

// Round 3
// 1222.570 us; speedup vs baseline: 2.6884x; 1.0487x over previous
//
#include <hip/hip_runtime.h>

#define N_NODES 50000
#define N_EDGES 400000
#define CHUNK   100000
#define NB_SCAN 196
#define BN_EPS  1e-5f
#define AGG_BLOCKS 3125   // 16 nodes per block -> 3125 * 16 = 50000 exactly
#define RED1_BLOCKS 64
#define RED1_ROWS 49      // ceil(3125/64)

typedef __attribute__((ext_vector_type(8))) short s16x8;
typedef __attribute__((ext_vector_type(4))) float f32x4;

__device__ __forceinline__ unsigned short f2bf(float x) {
    unsigned u = __float_as_uint(x);
    return (unsigned short)((u + 0x7fffu + ((u >> 16) & 1u)) >> 16);
}
__device__ __forceinline__ float bf2f(unsigned short b) {
    return __uint_as_float(((unsigned)b) << 16);
}

// CK-style direct global->LDS 16B load (linear LDS dest = wave base + lane*16)
__device__ __forceinline__ void gload_lds16(const void* g, void* lds) {
    auto gp = reinterpret_cast<const __attribute__((address_space(1))) unsigned int*>(
        reinterpret_cast<uintptr_t>(g));
    auto lp = reinterpret_cast<__attribute__((address_space(3))) unsigned int*>(
        reinterpret_cast<uintptr_t>(lds));
    __builtin_amdgcn_global_load_lds(gp, lp, 16, 0, 0);
}

// ---------------- utility ----------------
__global__ void zero_i32(int* p, int n) {
    int i = blockIdx.x * blockDim.x + threadIdx.x;
    if (i < n) p[i] = 0;
}
__global__ void count_deg(const int* __restrict__ dst, int* __restrict__ counts) {
    int e = blockIdx.x * blockDim.x + threadIdx.x;
    if (e < N_EDGES) atomicAdd(&counts[dst[e]], 1);
}
__global__ void isd_kernel(const int* __restrict__ counts, float* __restrict__ isd) {
    int i = blockIdx.x * blockDim.x + threadIdx.x;
    if (i < N_NODES) isd[i] = rsqrtf(1.0f + (float)counts[i]);
}

// ---------------- 3-phase scan ----------------
__global__ __launch_bounds__(256) void scan_reduce(const int* __restrict__ counts,
                                                   int* __restrict__ bsum) {
    __shared__ int sh[256];
    int t = threadIdx.x, b = blockIdx.x;
    int i = b * 256 + t;
    sh[t] = (i < N_NODES) ? counts[i] : 0;
    __syncthreads();
    for (int o = 128; o > 0; o >>= 1) {
        if (t < o) sh[t] += sh[t + o];
        __syncthreads();
    }
    if (t == 0) bsum[b] = sh[0];
}
__global__ __launch_bounds__(256) void scan_tops(const int* __restrict__ bsum,
                                                 int* __restrict__ boff, int nb,
                                                 int* __restrict__ total_out) {
    __shared__ int sh[256];
    int t = threadIdx.x;
    int v = (t < nb) ? bsum[t] : 0;
    sh[t] = v;
    __syncthreads();
    for (int o = 1; o < 256; o <<= 1) {
        int a = (t >= o) ? sh[t - o] : 0;
        __syncthreads();
        sh[t] += a;
        __syncthreads();
    }
    if (t < nb) boff[t] = sh[t] - v;
    if (t == 255) *total_out = sh[255];
}
__global__ __launch_bounds__(256) void scan_final(const int* __restrict__ counts,
                                                  const int* __restrict__ boff,
                                                  int* __restrict__ offsets) {
    __shared__ int sh[256];
    int t = threadIdx.x, b = blockIdx.x;
    int i = b * 256 + t;
    int v = (i < N_NODES) ? counts[i] : 0;
    sh[t] = v;
    __syncthreads();
    for (int o = 1; o < 256; o <<= 1) {
        int a = (t >= o) ? sh[t - o] : 0;
        __syncthreads();
        sh[t] += a;
        __syncthreads();
    }
    if (i < N_NODES) offsets[i] = boff[b] + sh[t] - v;
}

__global__ void fill_csr(const int* __restrict__ src, const int* __restrict__ dst,
                         const float* __restrict__ isd, const int* __restrict__ offsets,
                         int* __restrict__ cursor, int* __restrict__ srcS,
                         float* __restrict__ normS) {
    int e = blockIdx.x * blockDim.x + threadIdx.x;
    if (e >= N_EDGES) return;
    int s = src[e], d = dst[e];
    int pos = offsets[d] + atomicAdd(&cursor[d], 1);
    srcS[pos] = s;
    normS[pos] = isd[s] * isd[d];
}

// ---------------- conversions ----------------
__global__ void conv_f32_bf16(const float* __restrict__ in, unsigned short* __restrict__ out,
                              int n4) {
    int i = blockIdx.x * blockDim.x + threadIdx.x;
    if (i >= n4) return;
    float4 v = ((const float4*)in)[i];
    unsigned short o0 = f2bf(v.x), o1 = f2bf(v.y), o2 = f2bf(v.z), o3 = f2bf(v.w);
    unsigned r0 = ((unsigned)o1 << 16) | o0;
    unsigned r1 = ((unsigned)o3 << 16) | o2;
    ((uint2*)out)[i] = make_uint2(r0, r1);
}

// W [K][Nout] fp32 -> Wt [Nout][K] bf16
__global__ void transp_conv(const float* __restrict__ W, unsigned short* __restrict__ Wt,
                            int K, int Nout) {
    int idx = blockIdx.x * blockDim.x + threadIdx.x;
    if (idx >= K * Nout) return;
    int k = idx / Nout, n = idx % Nout;
    Wt[(size_t)n * K + k] = f2bf(W[idx]);
}

// ---------------- bf16 MFMA GEMM (m97 structure: global_load_lds staging) ----------------
// C[M][Nout] = A[M][K](bf16, lda) @ Wt[Nout][K](bf16)^T
// OUT_MODE: 0 = f32 out, 1 = bf16 out, 2 = fused 64->2 edge output (BN_T=64 only)
// LDS layout: [row][granule] with content[row][p] = A[row][ (p ^ f(row)) * 8 .. +8 ],
// f(row) = (row>>1)&3  -> ds_read_b128 hits exactly 2 lanes/bank (free, m136).
template <int BN_T, int OUT_MODE, int RELU, int BIAS>
__global__ __launch_bounds__(256) void gemm_mfma(const unsigned short* __restrict__ A, int lda,
                                                 const unsigned short* __restrict__ Wt,
                                                 const float* __restrict__ bias,
                                                 void* __restrict__ Cout, int ldc,
                                                 int M, int K,
                                                 const float* __restrict__ Wc5,
                                                 const float* __restrict__ bc5) {
    constexpr int MI = (BN_T == 128) ? 4 : 2;
    constexpr int NI = 4;
    __shared__ __align__(16) short As[128 * 32];
    __shared__ __align__(16) short Bs[BN_T * 32];

    const int tid = threadIdx.x;
    const int l = tid & 63;
    const int wv = tid >> 6;
    const int wrow = (BN_T == 128) ? (wv >> 1) * 64 : wv * 32;
    const int wcol = (BN_T == 128) ? (wv & 1) * 64 : 0;
    const int bm = blockIdx.x * 128;
    const int bn = blockIdx.y * BN_T;
    const int rsub = l >> 2;   // row within a 16-row issue
    const int gl = l & 3;      // linear granule this lane fills

    f32x4 acc[MI][NI] = {};

    for (int k0 = 0; k0 < K; k0 += 32) {
        // A: 2 issues/wave, each covers 16 rows x 64B (wave-uniform LDS base + lane*16B)
#pragma unroll
        for (int i = 0; i < 2; i++) {
            int lr = wv * 32 + i * 16 + rsub;
            int gr = bm + lr;
            if (gr >= M) gr = M - 1;
            int gsrc = gl ^ ((lr >> 1) & 3);
            gload_lds16(&A[(size_t)gr * lda + k0 + gsrc * 8],
                        &As[(wv * 32 + i * 16) * 32]);
        }
        // B: BN_T/64 issues/wave
#pragma unroll
        for (int i = 0; i < BN_T / 64; i++) {
            int base = (BN_T == 128) ? (wv * 32 + i * 16) : (wv * 16);
            int lr = base + rsub;
            int gsrc = gl ^ ((lr >> 1) & 3);
            gload_lds16(&Wt[(size_t)(bn + lr) * K + k0 + gsrc * 8],
                        &Bs[base * 32]);
        }
        __syncthreads();  // drains vmcnt(0): staged data visible

        s16x8 af[MI], bfr[NI];
        const int q = l >> 4;  // logical K-granule
#pragma unroll
        for (int mi = 0; mi < MI; mi++) {
            int r = wrow + mi * 16 + (l & 15);
            af[mi] = *(const s16x8*)(&As[r * 32 + ((q ^ ((r >> 1) & 3)) << 3)]);
        }
#pragma unroll
        for (int ni = 0; ni < NI; ni++) {
            int r = wcol + ni * 16 + (l & 15);
            bfr[ni] = *(const s16x8*)(&Bs[r * 32 + ((q ^ ((r >> 1) & 3)) << 3)]);
        }
#pragma unroll
        for (int mi = 0; mi < MI; mi++)
#pragma unroll
            for (int ni = 0; ni < NI; ni++)
                acc[mi][ni] = __builtin_amdgcn_mfma_f32_16x16x32_bf16(af[mi], bfr[ni],
                                                                      acc[mi][ni], 0, 0, 0);
        __syncthreads();  // protect LDS before next-tile staging
    }

    if (OUT_MODE == 2) {
        // fused: v = relu(acc + bc4), out[row][0..1] = v(64) @ Wc5 + bc5
        float* outp = (float*)Cout;
#pragma unroll
        for (int mi = 0; mi < MI; mi++) {
#pragma unroll
            for (int r = 0; r < 4; r++) {
                float p0 = 0.f, p1 = 0.f;
#pragma unroll
                for (int ni = 0; ni < NI; ni++) {
                    int col = wcol + ni * 16 + (l & 15);
                    float v = fmaxf(acc[mi][ni][r] + bias[col], 0.0f);
                    p0 += v * Wc5[col * 2 + 0];
                    p1 += v * Wc5[col * 2 + 1];
                }
#pragma unroll
                for (int o = 1; o < 16; o <<= 1) {
                    p0 += __shfl_xor(p0, o, 64);
                    p1 += __shfl_xor(p1, o, 64);
                }
                int row = bm + wrow + mi * 16 + (l >> 4) * 4 + r;
                if ((l & 15) == 0 && row < M) {
                    outp[(size_t)row * 2 + 0] = p0 + bc5[0];
                    outp[(size_t)row * 2 + 1] = p1 + bc5[1];
                }
            }
        }
        return;
    }

#pragma unroll
    for (int mi = 0; mi < MI; mi++) {
#pragma unroll
        for (int ni = 0; ni < NI; ni++) {
            int colB = bn + wcol + ni * 16 + (l & 15);
            float bv = BIAS ? bias[colB] : 0.0f;
#pragma unroll
            for (int r = 0; r < 4; r++) {
                int row = bm + wrow + mi * 16 + (l >> 4) * 4 + r;
                if (row < M) {
                    float v = acc[mi][ni][r] + bv;
                    if (RELU) v = fmaxf(v, 0.0f);
                    if (OUT_MODE == 1)
                        ((unsigned short*)Cout)[(size_t)row * ldc + colB] = f2bf(v);
                    else
                        ((float*)Cout)[(size_t)row * ldc + colB] = v;
                }
            }
        }
    }
}

// ---------------- fused GCN aggregation + BN-stat partials ----------------
// 4 waves/block, 4 nodes/wave (16 nodes/block). Writes bf16 agg output and
// per-block [1024] partial {sum, sumsq} rows for BN.
__global__ __launch_bounds__(256) void aggregate_fused(
    const unsigned short* __restrict__ hwb, const float* __restrict__ isd,
    const int* __restrict__ offsets, const int* __restrict__ srcS,
    const float* __restrict__ normS, const float* __restrict__ b1,
    const float* __restrict__ b2, unsigned short* __restrict__ hagg,
    float* __restrict__ partials) {
    __shared__ float sstat[1024];
    int tid = threadIdx.x;
    for (int i = tid; i < 1024; i += 256) sstat[i] = 0.f;
    __syncthreads();
    int wv = tid >> 6, l = tid & 63;
    int c0 = l * 8;
    float bias8[8];
    {
        const float* bp = (c0 < 256) ? (b1 + c0) : (b2 + (c0 - 256));
        float4 b0 = *(const float4*)bp;
        float4 bv1 = *(const float4*)(bp + 4);
        bias8[0] = b0.x; bias8[1] = b0.y; bias8[2] = b0.z; bias8[3] = b0.w;
        bias8[4] = bv1.x; bias8[5] = bv1.y; bias8[6] = bv1.z; bias8[7] = bv1.w;
    }
    float sacc[8] = {}, qacc[8] = {};
    int nbase = blockIdx.x * 16 + wv * 4;
    for (int nn = 0; nn < 4; nn++) {
        int n = nbase + nn;
        float acc[8] = {};
        int e0 = offsets[n], e1 = offsets[n + 1];
        for (int k = e0; k < e1; k++) {
            int s = srcS[k];
            float wgt = normS[k];
            union { int4 v; unsigned short u[8]; } U;
            U.v = *(const int4*)(&hwb[(size_t)s * 512 + c0]);
#pragma unroll
            for (int j = 0; j < 8; j++) acc[j] += wgt * bf2f(U.u[j]);
        }
        float si = isd[n]; si *= si;
        union { int4 v; unsigned short u[8]; } U;
        U.v = *(const int4*)(&hwb[(size_t)n * 512 + c0]);
        unsigned short os[8];
#pragma unroll
        for (int j = 0; j < 8; j++) {
            acc[j] += si * bf2f(U.u[j]) + bias8[j];
            sacc[j] += acc[j];
            qacc[j] += acc[j] * acc[j];
            os[j] = f2bf(acc[j]);
        }
        int4 ov;
        ov.x = (int)(((unsigned)os[1] << 16) | os[0]);
        ov.y = (int)(((unsigned)os[3] << 16) | os[2]);
        ov.z = (int)(((unsigned)os[5] << 16) | os[4]);
        ov.w = (int)(((unsigned)os[7] << 16) | os[6]);
        *(int4*)(&hagg[(size_t)n * 512 + c0]) = ov;
    }
#pragma unroll
    for (int j = 0; j < 8; j++) {
        atomicAdd(&sstat[c0 + j], sacc[j]);
        atomicAdd(&sstat[512 + c0 + j], qacc[j]);
    }
    __syncthreads();
    float* prow = partials + (size_t)blockIdx.x * 1024;
    for (int i = tid; i < 1024; i += 256) prow[i] = sstat[i];
}

// reduce 3125 partial rows -> 64 rows
__global__ __launch_bounds__(256) void red1(const float* __restrict__ partials,
                                            float* __restrict__ p2) {
    int b = blockIdx.x, t = threadIdx.x;
    float a[4] = {};
    int r0 = b * RED1_ROWS;
    int r1 = r0 + RED1_ROWS;
    if (r1 > AGG_BLOCKS) r1 = AGG_BLOCKS;
    for (int r = r0; r < r1; r++) {
        const float* row = partials + (size_t)r * 1024;
#pragma unroll
        for (int j = 0; j < 4; j++) a[j] += row[t + j * 256];
    }
#pragma unroll
    for (int j = 0; j < 4; j++) p2[b * 1024 + t + j * 256] = a[j];
}

// reduce 64 rows -> per-channel affine AB: y = x*AB[c] + AB[512+c]
__global__ __launch_bounds__(256) void red2(const float* __restrict__ p2,
                                            const float* __restrict__ g,
                                            const float* __restrict__ be,
                                            float* __restrict__ AB) {
    int t = threadIdx.x;
#pragma unroll
    for (int h = 0; h < 2; h++) {
        int c = t + h * 256;
        float S = 0.f, Q = 0.f;
        for (int r = 0; r < RED1_BLOCKS; r++) {
            S += p2[r * 1024 + c];
            Q += p2[r * 1024 + 512 + c];
        }
        float m = S * (1.0f / N_NODES);
        float var = Q * (1.0f / N_NODES) - m * m;
        float sc = g[c & 255] * rsqrtf(var + BN_EPS);
        AB[c] = sc;
        AB[512 + c] = be[c & 255] - m * sc;
    }
}

// y = relu(x*A + B), bf16 in/out, 512-wide
__global__ __launch_bounds__(256) void bn_apply(const unsigned short* __restrict__ h,
                                                const float* __restrict__ AB,
                                                unsigned short* __restrict__ outp) {
    int i8 = blockIdx.x * blockDim.x + threadIdx.x;
    if (i8 >= N_NODES * 512 / 8) return;
    int c8 = (i8 & 63) * 8;
    union { int4 v; unsigned short u[8]; } U;
    U.v = *(const int4*)(&h[(size_t)i8 * 8]);
    unsigned short os[8];
#pragma unroll
    for (int j = 0; j < 8; j++) {
        int c = c8 + j;
        float y = bf2f(U.u[j]) * AB[c] + AB[512 + c];
        os[j] = f2bf(fmaxf(y, 0.0f));
    }
    int4 ov;
    ov.x = (int)(((unsigned)os[1] << 16) | os[0]);
    ov.y = (int)(((unsigned)os[3] << 16) | os[2]);
    ov.z = (int)(((unsigned)os[5] << 16) | os[4]);
    ov.w = (int)(((unsigned)os[7] << 16) | os[6]);
    *(int4*)(&outp[(size_t)i8 * 8]) = ov;
}

// final layer: hc = relu(bn(h1)) + relu(bn(h2)), bf16 out 256-wide
__global__ __launch_bounds__(256) void bn_apply_final(const unsigned short* __restrict__ h,
                                                      const float* __restrict__ AB,
                                                      unsigned short* __restrict__ hc) {
    int i8 = blockIdx.x * blockDim.x + threadIdx.x;
    if (i8 >= N_NODES * 256 / 8) return;
    int n = i8 >> 5;
    int c8 = (i8 & 31) * 8;
    union { int4 v; unsigned short u[8]; } U1, U2;
    U1.v = *(const int4*)(&h[(size_t)n * 512 + c8]);
    U2.v = *(const int4*)(&h[(size_t)n * 512 + 256 + c8]);
    unsigned short os[8];
#pragma unroll
    for (int j = 0; j < 8; j++) {
        int c = c8 + j;
        float y1 = fmaxf(bf2f(U1.u[j]) * AB[c] + AB[512 + c], 0.0f);
        int c2 = c + 256;
        float y2 = fmaxf(bf2f(U2.u[j]) * AB[c2] + AB[512 + c2], 0.0f);
        os[j] = f2bf(y1 + y2);
    }
    int4 ov;
    ov.x = (int)(((unsigned)os[1] << 16) | os[0]);
    ov.y = (int)(((unsigned)os[3] << 16) | os[2]);
    ov.z = (int)(((unsigned)os[5] << 16) | os[4]);
    ov.w = (int)(((unsigned)os[7] << 16) | os[6]);
    *(int4*)(&hc[(size_t)i8 * 8]) = ov;
}

// ---------------- edge MLP layer 1 ----------------
__global__ __launch_bounds__(256) void edge_l1(const unsigned short* __restrict__ PQ,
                                               const int* __restrict__ src,
                                               const int* __restrict__ dst,
                                               const float* __restrict__ ea,
                                               const float* __restrict__ Wc1e,
                                               const float* __restrict__ bc1,
                                               unsigned short* __restrict__ e1out,
                                               int e_base, int count) {
    int wid = threadIdx.x >> 6, l = threadIdx.x & 63;
    int el = blockIdx.x * 4 + wid;
    if (el >= count) return;
    int e = e_base + el;
    int s = src[e], d = dst[e];
    int c0 = l * 4;
    union { int2 v; unsigned short u[4]; } Pu, Qu;
    Pu.v = *(const int2*)(&PQ[(size_t)s * 512 + c0]);
    Qu.v = *(const int2*)(&PQ[(size_t)d * 512 + 256 + c0]);
    float v[4];
#pragma unroll
    for (int j = 0; j < 4; j++) v[j] = bf2f(Pu.u[j]) + bf2f(Qu.u[j]) + bc1[c0 + j];
#pragma unroll
    for (int jj = 0; jj < 8; jj++) {
        float av = ea[(size_t)e * 8 + jj];
        float4 w = *(const float4*)(&Wc1e[jj * 256 + c0]);
        v[0] += av * w.x; v[1] += av * w.y; v[2] += av * w.z; v[3] += av * w.w;
    }
    unsigned short os[4];
#pragma unroll
    for (int j = 0; j < 4; j++) os[j] = f2bf(fmaxf(v[j], 0.0f));
    unsigned r0 = ((unsigned)os[1] << 16) | os[0];
    unsigned r1 = ((unsigned)os[3] << 16) | os[2];
    *(uint2*)(&e1out[(size_t)el * 256 + c0]) = make_uint2(r0, r1);
}

// ---------------- launch ----------------
extern "C" void kernel_launch(void* const* d_in, const int* in_sizes, int n_in,
                              void* d_out, int out_size, void* d_ws, size_t ws_size,
                              hipStream_t stream) {
    const float* x   = (const float*)d_in[0];
    const int*   ei  = (const int*)d_in[1];
    const float* ea  = (const float*)d_in[2];
    const float* W11 = (const float*)d_in[3];
    const float* b11 = (const float*)d_in[4];
    const float* W12 = (const float*)d_in[5];
    const float* b12 = (const float*)d_in[6];
    const float* W13 = (const float*)d_in[7];
    const float* b13 = (const float*)d_in[8];
    const float* W21 = (const float*)d_in[9];
    const float* b21 = (const float*)d_in[10];
    const float* W22 = (const float*)d_in[11];
    const float* b22 = (const float*)d_in[12];
    const float* W23 = (const float*)d_in[13];
    const float* b23 = (const float*)d_in[14];
    const float* g1  = (const float*)d_in[15];
    const float* be1 = (const float*)d_in[16];
    const float* g2  = (const float*)d_in[17];
    const float* be2 = (const float*)d_in[18];
    const float* g3  = (const float*)d_in[19];
    const float* be3 = (const float*)d_in[20];
    const float* Wc1 = (const float*)d_in[21];
    const float* bc1 = (const float*)d_in[22];
    const float* Wc2 = (const float*)d_in[23];
    const float* bc2 = (const float*)d_in[24];
    const float* Wc3 = (const float*)d_in[25];
    const float* bc3 = (const float*)d_in[26];
    const float* Wc4 = (const float*)d_in[27];
    const float* bc4 = (const float*)d_in[28];
    const float* Wc5 = (const float*)d_in[29];
    const float* bc5 = (const float*)d_in[30];

    const int* src = ei;
    const int* dst = ei + N_EDGES;
    float* out = (float*)d_out;

    // ---- workspace carve ----
    char* w = (char*)d_ws;
    auto alloc = [&](size_t bytes) {
        char* p = w;
        w += (bytes + 255) & ~(size_t)255;
        return p;
    };
    float* isd     = (float*)alloc(N_NODES * 4);
    float* normS   = (float*)alloc(N_EDGES * 4);
    int*   srcS    = (int*)alloc(N_EDGES * 4);
    int*   counts  = (int*)alloc((N_NODES + 4) * 4);
    int*   offsets = (int*)alloc((N_NODES + 4) * 4);
    int*   bsum    = (int*)alloc(256 * 4);
    int*   boff    = (int*)alloc(256 * 4);
    float* AB      = (float*)alloc(1024 * 4);
    float* p2      = (float*)alloc(RED1_BLOCKS * 1024 * 4);
    unsigned short* W11t = (unsigned short*)alloc(256 * 128 * 2);
    unsigned short* W21t = (unsigned short*)alloc(256 * 128 * 2);
    unsigned short* W12t = (unsigned short*)alloc(256 * 256 * 2);
    unsigned short* W22t = (unsigned short*)alloc(256 * 256 * 2);
    unsigned short* W13t = (unsigned short*)alloc(256 * 256 * 2);
    unsigned short* W23t = (unsigned short*)alloc(256 * 256 * 2);
    unsigned short* WPQt = (unsigned short*)alloc(512 * 256 * 2);
    unsigned short* Wc2t = (unsigned short*)alloc(256 * 256 * 2);
    unsigned short* Wc3t = (unsigned short*)alloc(128 * 256 * 2);
    unsigned short* Wc4t = (unsigned short*)alloc(64 * 128 * 2);
    unsigned short* xb   = (unsigned short*)alloc((size_t)N_NODES * 128 * 2);
    unsigned short* hb   = (unsigned short*)alloc((size_t)N_NODES * 512 * 2);
    unsigned short* hwb  = (unsigned short*)alloc((size_t)N_NODES * 512 * 2);
    unsigned short* hagg = (unsigned short*)alloc((size_t)N_NODES * 512 * 2);
    unsigned short* hc   = (unsigned short*)alloc((size_t)N_NODES * 256 * 2);
    float* partials = (float*)alloc((size_t)AGG_BLOCKS * 1024 * 4);
    (void)ws_size;

    // edge-phase aliases (dead buffers): e1 <- hagg region (51.2MB),
    // e2 <- xb+hb region (64MB contiguous), e3 <- e1 region
    unsigned short* e1 = hagg;
    unsigned short* e2 = xb;
    unsigned short* e3 = hagg;

    // ---- CSR build ----
    zero_i32<<<(N_NODES + 256) / 256, 256, 0, stream>>>(counts, N_NODES + 1);
    count_deg<<<(N_EDGES + 255) / 256, 256, 0, stream>>>(dst, counts);
    isd_kernel<<<(N_NODES + 255) / 256, 256, 0, stream>>>(counts, isd);
    scan_reduce<<<NB_SCAN, 256, 0, stream>>>(counts, bsum);
    scan_tops<<<1, 256, 0, stream>>>(bsum, boff, NB_SCAN, offsets + N_NODES);
    scan_final<<<NB_SCAN, 256, 0, stream>>>(counts, boff, offsets);
    zero_i32<<<(N_NODES + 255) / 256, 256, 0, stream>>>(counts, N_NODES);
    fill_csr<<<(N_EDGES + 255) / 256, 256, 0, stream>>>(src, dst, isd, offsets, counts,
                                                        srcS, normS);

    // ---- preconvert ----
    conv_f32_bf16<<<(N_NODES * 128 / 4 + 255) / 256, 256, 0, stream>>>(x, xb,
                                                                        N_NODES * 128 / 4);
    auto tr = [&](const float* W, unsigned short* Wt, int K, int Nout) {
        transp_conv<<<(K * Nout + 255) / 256, 256, 0, stream>>>(W, Wt, K, Nout);
    };
    tr(W11, W11t, 128, 256); tr(W21, W21t, 128, 256);
    tr(W12, W12t, 256, 256); tr(W22, W22t, 256, 256);
    tr(W13, W13t, 256, 256); tr(W23, W23t, 256, 256);
    tr(Wc1, WPQt, 256, 256);
    tr(Wc1 + 256 * 256, WPQt + 256 * 256, 256, 256);
    tr(Wc2, Wc2t, 256, 256);
    tr(Wc3, Wc3t, 256, 128);
    tr(Wc4, Wc4t, 128, 64);

    // ---- 3 GCN layers ----
    const unsigned short* Wat[3] = {W11t, W12t, W13t};
    const unsigned short* Wbt[3] = {W21t, W22t, W23t};
    const float* ba[3] = {b11, b12, b13};
    const float* bb[3] = {b21, b22, b23};
    const float* gs[3] = {g1, g2, g3};
    const float* bes[3] = {be1, be2, be3};

    int gx_n = (N_NODES + 127) / 128;  // 391
    for (int l = 0; l < 3; l++) {
        if (l == 0) {
            gemm_mfma<128, 1, 0, 0><<<dim3(gx_n, 2), 256, 0, stream>>>(
                xb, 128, Wat[0], nullptr, hwb, 512, N_NODES, 128, nullptr, nullptr);
            gemm_mfma<128, 1, 0, 0><<<dim3(gx_n, 2), 256, 0, stream>>>(
                xb, 128, Wbt[0], nullptr, hwb + 256, 512, N_NODES, 128, nullptr, nullptr);
        } else {
            gemm_mfma<128, 1, 0, 0><<<dim3(gx_n, 2), 256, 0, stream>>>(
                hb, 512, Wat[l], nullptr, hwb, 512, N_NODES, 256, nullptr, nullptr);
            gemm_mfma<128, 1, 0, 0><<<dim3(gx_n, 2), 256, 0, stream>>>(
                hb + 256, 512, Wbt[l], nullptr, hwb + 256, 512, N_NODES, 256, nullptr, nullptr);
        }
        aggregate_fused<<<AGG_BLOCKS, 256, 0, stream>>>(hwb, isd, offsets, srcS, normS,
                                                        ba[l], bb[l], hagg, partials);
        red1<<<RED1_BLOCKS, 256, 0, stream>>>(partials, p2);
        red2<<<1, 256, 0, stream>>>(p2, gs[l], bes[l], AB);
        if (l < 2) {
            bn_apply<<<(N_NODES * 512 / 8 + 255) / 256, 256, 0, stream>>>(hagg, AB, hb);
        } else {
            bn_apply_final<<<(N_NODES * 256 / 8 + 255) / 256, 256, 0, stream>>>(hagg, AB, hc);
        }
    }

    // ---- PQ = hc @ [Wc1_P | Wc1_Q] -> hwb [N][512] bf16 ----
    gemm_mfma<128, 1, 0, 0><<<dim3(gx_n, 4), 256, 0, stream>>>(hc, 256, WPQt, nullptr,
                                                               hwb, 512, N_NODES, 256,
                                                               nullptr, nullptr);

    // ---- edge MLP in chunks ----
    int gx_e = (CHUNK + 127) / 128;  // 782
    for (int c0 = 0; c0 < N_EDGES; c0 += CHUNK) {
        int cnt = CHUNK;
        edge_l1<<<(cnt + 3) / 4, 256, 0, stream>>>(hwb, src, dst, ea, Wc1 + 512 * 256, bc1,
                                                   e1, c0, cnt);
        gemm_mfma<128, 1, 1, 1><<<dim3(gx_e, 2), 256, 0, stream>>>(e1, 256, Wc2t, bc2,
                                                                   e2, 256, cnt, 256,
                                                                   nullptr, nullptr);
        gemm_mfma<128, 1, 1, 1><<<dim3(gx_e, 1), 256, 0, stream>>>(e2, 256, Wc3t, bc3,
                                                                   e3, 128, cnt, 256,
                                                                   nullptr, nullptr);
        gemm_mfma<64, 2, 1, 1><<<dim3(gx_e, 1), 256, 0, stream>>>(e3, 128, Wc4t, bc4,
                                                                  out + (size_t)c0 * 2, 0,
                                                                  cnt, 128, Wc5, bc5);
    }
}

// Round 5
// 1073.662 us; speedup vs baseline: 3.0612x; 1.1387x over previous
//
#include <hip/hip_runtime.h>

#define N_NODES 50000
#define N_EDGES 400000
#define CHUNK   100000
#define NB_SCAN 196
#define BN_EPS  1e-5f
#define STAT_BLOCKS 128

typedef __attribute__((ext_vector_type(8))) short s16x8;
typedef __attribute__((ext_vector_type(4))) float f32x4;

__device__ __forceinline__ unsigned short f2bf(float x) {
    unsigned u = __float_as_uint(x);
    return (unsigned short)((u + 0x7fffu + ((u >> 16) & 1u)) >> 16);
}
__device__ __forceinline__ float bf2f(unsigned short b) {
    return __uint_as_float(((unsigned)b) << 16);
}

// direct global->LDS 16B load (linear LDS dest = wave base + lane*16)
__device__ __forceinline__ void gload_lds16(const void* g, void* lds) {
    auto gp = reinterpret_cast<const __attribute__((address_space(1))) unsigned int*>(
        reinterpret_cast<uintptr_t>(g));
    auto lp = reinterpret_cast<__attribute__((address_space(3))) unsigned int*>(
        reinterpret_cast<uintptr_t>(lds));
    __builtin_amdgcn_global_load_lds(gp, lp, 16, 0, 0);
}

// ---------------- utility ----------------
__global__ void zero_i32(int* p, int n) {
    int i = blockIdx.x * blockDim.x + threadIdx.x;
    if (i < n) p[i] = 0;
}
__global__ void zero_f32(float* p, int n) {
    int i = blockIdx.x * blockDim.x + threadIdx.x;
    if (i < n) p[i] = 0.0f;
}
__global__ void count_deg(const int* __restrict__ dst, int* __restrict__ counts) {
    int e = blockIdx.x * blockDim.x + threadIdx.x;
    if (e < N_EDGES) atomicAdd(&counts[dst[e]], 1);
}
__global__ void isd_kernel(const int* __restrict__ counts, float* __restrict__ isd) {
    int i = blockIdx.x * blockDim.x + threadIdx.x;
    if (i < N_NODES) isd[i] = rsqrtf(1.0f + (float)counts[i]);
}

// ---------------- 3-phase scan ----------------
__global__ __launch_bounds__(256) void scan_reduce(const int* __restrict__ counts,
                                                   int* __restrict__ bsum) {
    __shared__ int sh[256];
    int t = threadIdx.x, b = blockIdx.x;
    int i = b * 256 + t;
    sh[t] = (i < N_NODES) ? counts[i] : 0;
    __syncthreads();
    for (int o = 128; o > 0; o >>= 1) {
        if (t < o) sh[t] += sh[t + o];
        __syncthreads();
    }
    if (t == 0) bsum[b] = sh[0];
}
__global__ __launch_bounds__(256) void scan_tops(const int* __restrict__ bsum,
                                                 int* __restrict__ boff, int nb,
                                                 int* __restrict__ total_out) {
    __shared__ int sh[256];
    int t = threadIdx.x;
    int v = (t < nb) ? bsum[t] : 0;
    sh[t] = v;
    __syncthreads();
    for (int o = 1; o < 256; o <<= 1) {
        int a = (t >= o) ? sh[t - o] : 0;
        __syncthreads();
        sh[t] += a;
        __syncthreads();
    }
    if (t < nb) boff[t] = sh[t] - v;
    if (t == 255) *total_out = sh[255];
}
__global__ __launch_bounds__(256) void scan_final(const int* __restrict__ counts,
                                                  const int* __restrict__ boff,
                                                  int* __restrict__ offsets) {
    __shared__ int sh[256];
    int t = threadIdx.x, b = blockIdx.x;
    int i = b * 256 + t;
    int v = (i < N_NODES) ? counts[i] : 0;
    sh[t] = v;
    __syncthreads();
    for (int o = 1; o < 256; o <<= 1) {
        int a = (t >= o) ? sh[t - o] : 0;
        __syncthreads();
        sh[t] += a;
        __syncthreads();
    }
    if (i < N_NODES) offsets[i] = boff[b] + sh[t] - v;
}

// packed CSR entry: (src, norm) as int2
__global__ void fill_csr(const int* __restrict__ src, const int* __restrict__ dst,
                         const float* __restrict__ isd, const int* __restrict__ offsets,
                         int* __restrict__ cursor, int2* __restrict__ pk) {
    int e = blockIdx.x * blockDim.x + threadIdx.x;
    if (e >= N_EDGES) return;
    int s = src[e], d = dst[e];
    int pos = offsets[d] + atomicAdd(&cursor[d], 1);
    pk[pos] = make_int2(s, __float_as_int(isd[s] * isd[d]));
}

// ---------------- conversions ----------------
__global__ void conv_f32_bf16(const float* __restrict__ in, unsigned short* __restrict__ out,
                              int n4) {
    int i = blockIdx.x * blockDim.x + threadIdx.x;
    if (i >= n4) return;
    float4 v = ((const float4*)in)[i];
    unsigned short o0 = f2bf(v.x), o1 = f2bf(v.y), o2 = f2bf(v.z), o3 = f2bf(v.w);
    ((uint2*)out)[i] = make_uint2(((unsigned)o1 << 16) | o0, ((unsigned)o3 << 16) | o2);
}

__global__ void transp_conv(const float* __restrict__ W, unsigned short* __restrict__ Wt,
                            int K, int Nout) {
    int idx = blockIdx.x * blockDim.x + threadIdx.x;
    if (idx >= K * Nout) return;
    int k = idx / Nout, n = idx % Nout;
    Wt[(size_t)n * K + k] = f2bf(W[idx]);
}

// ---------------- bf16 MFMA GEMM (global_load_lds staging) ----------------
// C[M][Nout] = A[M][K] @ Wt[Nout][K]^T. OUT_MODE: 0=f32, 1=bf16, 2=fused 64->2 out.
// DUAL: grid.y=4, half=(y>>1) selects {A,Wt} vs {A2,Wt2}, output col offset half*256.
template <int BN_T, int OUT_MODE, int RELU, int BIAS, int DUAL>
__global__ __launch_bounds__(256) void gemm_mfma(const unsigned short* __restrict__ A, int lda,
                                                 const unsigned short* __restrict__ Wt,
                                                 const float* __restrict__ bias,
                                                 void* __restrict__ Cout, int ldc,
                                                 int M, int K,
                                                 const float* __restrict__ Wc5,
                                                 const float* __restrict__ bc5,
                                                 const unsigned short* __restrict__ A2,
                                                 const unsigned short* __restrict__ Wt2) {
    constexpr int MI = (BN_T == 128) ? 4 : 2;
    constexpr int NI = 4;
    __shared__ __align__(16) short As[128 * 32];
    __shared__ __align__(16) short Bs[BN_T * 32];

    const int tid = threadIdx.x;
    const int l = tid & 63;
    const int wv = tid >> 6;
    const int wrow = (BN_T == 128) ? (wv >> 1) * 64 : wv * 32;
    const int wcol = (BN_T == 128) ? (wv & 1) * 64 : 0;
    const int bm = blockIdx.x * 128;
    int bn, coloff;
    const unsigned short* Ause;
    const unsigned short* Wuse;
    if (DUAL) {
        int half_ = blockIdx.y >> 1;
        bn = (blockIdx.y & 1) * BN_T;
        coloff = half_ * 256;
        Ause = half_ ? A2 : A;
        Wuse = half_ ? Wt2 : Wt;
    } else {
        bn = blockIdx.y * BN_T;
        coloff = 0;
        Ause = A;
        Wuse = Wt;
    }
    const int rsub = l >> 2;
    const int gl = l & 3;

    f32x4 acc[MI][NI] = {};

    for (int k0 = 0; k0 < K; k0 += 32) {
#pragma unroll
        for (int i = 0; i < 2; i++) {
            int lr = wv * 32 + i * 16 + rsub;
            int gr = bm + lr;
            if (gr >= M) gr = M - 1;
            int gsrc = gl ^ ((lr >> 1) & 3);
            gload_lds16(&Ause[(size_t)gr * lda + k0 + gsrc * 8],
                        &As[(wv * 32 + i * 16) * 32]);
        }
#pragma unroll
        for (int i = 0; i < BN_T / 64; i++) {
            int base = (BN_T == 128) ? (wv * 32 + i * 16) : (wv * 16);
            int lr = base + rsub;
            int gsrc = gl ^ ((lr >> 1) & 3);
            gload_lds16(&Wuse[(size_t)(bn + lr) * K + k0 + gsrc * 8],
                        &Bs[base * 32]);
        }
        __syncthreads();

        s16x8 af[MI], bfr[NI];
        const int q = l >> 4;
#pragma unroll
        for (int mi = 0; mi < MI; mi++) {
            int r = wrow + mi * 16 + (l & 15);
            af[mi] = *(const s16x8*)(&As[r * 32 + ((q ^ ((r >> 1) & 3)) << 3)]);
        }
#pragma unroll
        for (int ni = 0; ni < NI; ni++) {
            int r = wcol + ni * 16 + (l & 15);
            bfr[ni] = *(const s16x8*)(&Bs[r * 32 + ((q ^ ((r >> 1) & 3)) << 3)]);
        }
#pragma unroll
        for (int mi = 0; mi < MI; mi++)
#pragma unroll
            for (int ni = 0; ni < NI; ni++)
                acc[mi][ni] = __builtin_amdgcn_mfma_f32_16x16x32_bf16(af[mi], bfr[ni],
                                                                      acc[mi][ni], 0, 0, 0);
        __syncthreads();
    }

    if (OUT_MODE == 2) {
        float* outp = (float*)Cout;
#pragma unroll
        for (int mi = 0; mi < MI; mi++) {
#pragma unroll
            for (int r = 0; r < 4; r++) {
                float p0 = 0.f, p1 = 0.f;
#pragma unroll
                for (int ni = 0; ni < NI; ni++) {
                    int col = wcol + ni * 16 + (l & 15);
                    float v = fmaxf(acc[mi][ni][r] + bias[col], 0.0f);
                    p0 += v * Wc5[col * 2 + 0];
                    p1 += v * Wc5[col * 2 + 1];
                }
#pragma unroll
                for (int o = 1; o < 16; o <<= 1) {
                    p0 += __shfl_xor(p0, o, 64);
                    p1 += __shfl_xor(p1, o, 64);
                }
                int row = bm + wrow + mi * 16 + (l >> 4) * 4 + r;
                if ((l & 15) == 0 && row < M) {
                    outp[(size_t)row * 2 + 0] = p0 + bc5[0];
                    outp[(size_t)row * 2 + 1] = p1 + bc5[1];
                }
            }
        }
        return;
    }

#pragma unroll
    for (int mi = 0; mi < MI; mi++) {
#pragma unroll
        for (int ni = 0; ni < NI; ni++) {
            int colB = coloff + bn + wcol + ni * 16 + (l & 15);
            float bv = BIAS ? bias[colB] : 0.0f;
#pragma unroll
            for (int r = 0; r < 4; r++) {
                int row = bm + wrow + mi * 16 + (l >> 4) * 4 + r;
                if (row < M) {
                    float v = acc[mi][ni][r] + bv;
                    if (RELU) v = fmaxf(v, 0.0f);
                    if (OUT_MODE == 1)
                        ((unsigned short*)Cout)[(size_t)row * ldc + colB] = f2bf(v);
                    else
                        ((float*)Cout)[(size_t)row * ldc + colB] = v;
                }
            }
        }
    }
}

// ---------------- GCN aggregation: 1 node/wave, packed pairs, bf16 out ----------------
__global__ __launch_bounds__(256) void aggregate2(const unsigned short* __restrict__ hwb,
                                                  const float* __restrict__ isd,
                                                  const int* __restrict__ offsets,
                                                  const int2* __restrict__ pk,
                                                  const float* __restrict__ b1,
                                                  const float* __restrict__ b2,
                                                  unsigned short* __restrict__ hagg) {
    int wv = threadIdx.x >> 6, l = threadIdx.x & 63;
    int n = blockIdx.x * 4 + wv;
    int c0 = l * 8;
    float acc[8] = {};
    int e0 = offsets[n], e1 = offsets[n + 1];
    int k = e0;
    for (; k + 2 <= e1; k += 2) {
        int2 p0 = pk[k], p1 = pk[k + 1];
        union { int4 v; unsigned short u[8]; } U0, U1;
        U0.v = *(const int4*)(&hwb[(size_t)p0.x * 512 + c0]);
        U1.v = *(const int4*)(&hwb[(size_t)p1.x * 512 + c0]);
        float w0 = __int_as_float(p0.y), w1 = __int_as_float(p1.y);
#pragma unroll
        for (int j = 0; j < 8; j++)
            acc[j] = fmaf(w0, bf2f(U0.u[j]), fmaf(w1, bf2f(U1.u[j]), acc[j]));
    }
    if (k < e1) {
        int2 p0 = pk[k];
        union { int4 v; unsigned short u[8]; } U0;
        U0.v = *(const int4*)(&hwb[(size_t)p0.x * 512 + c0]);
        float w0 = __int_as_float(p0.y);
#pragma unroll
        for (int j = 0; j < 8; j++) acc[j] = fmaf(w0, bf2f(U0.u[j]), acc[j]);
    }
    float si = isd[n]; si *= si;
    union { int4 v; unsigned short u[8]; } U;
    U.v = *(const int4*)(&hwb[(size_t)n * 512 + c0]);
    const float* bp = (c0 < 256) ? (b1 + c0) : (b2 + (c0 - 256));
    unsigned short os[8];
#pragma unroll
    for (int j = 0; j < 8; j++) {
        acc[j] = fmaf(si, bf2f(U.u[j]), acc[j]) + bp[j];
        os[j] = f2bf(acc[j]);
    }
    int4 ov;
    ov.x = (int)(((unsigned)os[1] << 16) | os[0]);
    ov.y = (int)(((unsigned)os[3] << 16) | os[2]);
    ov.z = (int)(((unsigned)os[5] << 16) | os[4]);
    ov.w = (int)(((unsigned)os[7] << 16) | os[6]);
    *(int4*)(&hagg[(size_t)n * 512 + c0]) = ov;
}

// ---------------- BN stats over bf16 [N][512]: stats[c]=sum, stats[512+c]=sumsq ----------------
__global__ __launch_bounds__(256) void bn_stats2(const unsigned short* __restrict__ h,
                                                 float* __restrict__ stats) {
    __shared__ float sh[4][1024];
    int t = threadIdx.x;
    int wv = t >> 6, l = t & 63;
    int c0 = l * 8;
    float s[8] = {}, q[8] = {};
    for (int n = blockIdx.x * 4 + wv; n < N_NODES; n += STAT_BLOCKS * 4) {
        union { int4 v; unsigned short u[8]; } U;
        U.v = *(const int4*)(&h[(size_t)n * 512 + c0]);
#pragma unroll
        for (int j = 0; j < 8; j++) {
            float x = bf2f(U.u[j]);
            s[j] += x;
            q[j] = fmaf(x, x, q[j]);
        }
    }
#pragma unroll
    for (int j = 0; j < 8; j++) {
        sh[wv][c0 + j] = s[j];
        sh[wv][512 + c0 + j] = q[j];
    }
    __syncthreads();
    for (int i = t; i < 1024; i += 256) {
        float a = sh[0][i] + sh[1][i] + sh[2][i] + sh[3][i];
        atomicAdd(&stats[i], a);
    }
}

// stats -> per-channel affine AB: y = x*AB[c] + AB[512+c]
__global__ __launch_bounds__(256) void bn_ab(const float* __restrict__ stats,
                                             const float* __restrict__ g,
                                             const float* __restrict__ be,
                                             float* __restrict__ AB) {
    int t = threadIdx.x;
#pragma unroll
    for (int h = 0; h < 2; h++) {
        int c = t + h * 256;
        float m = stats[c] * (1.0f / N_NODES);
        float var = stats[512 + c] * (1.0f / N_NODES) - m * m;
        float sc = g[c & 255] * rsqrtf(var + BN_EPS);
        AB[c] = sc;
        AB[512 + c] = be[c & 255] - m * sc;
    }
}

// y = relu(x*A + B), bf16 in/out, 512-wide
__global__ __launch_bounds__(256) void bn_apply(const unsigned short* __restrict__ h,
                                                const float* __restrict__ AB,
                                                unsigned short* __restrict__ outp) {
    int i8 = blockIdx.x * blockDim.x + threadIdx.x;
    if (i8 >= N_NODES * 512 / 8) return;
    int c8 = (i8 & 63) * 8;
    union { int4 v; unsigned short u[8]; } U;
    U.v = *(const int4*)(&h[(size_t)i8 * 8]);
    unsigned short os[8];
#pragma unroll
    for (int j = 0; j < 8; j++) {
        int c = c8 + j;
        float y = fmaf(bf2f(U.u[j]), AB[c], AB[512 + c]);
        os[j] = f2bf(fmaxf(y, 0.0f));
    }
    int4 ov;
    ov.x = (int)(((unsigned)os[1] << 16) | os[0]);
    ov.y = (int)(((unsigned)os[3] << 16) | os[2]);
    ov.z = (int)(((unsigned)os[5] << 16) | os[4]);
    ov.w = (int)(((unsigned)os[7] << 16) | os[6]);
    *(int4*)(&outp[(size_t)i8 * 8]) = ov;
}

// final: hc = relu(bn(h1)) + relu(bn(h2)), bf16 out 256-wide
__global__ __launch_bounds__(256) void bn_apply_final(const unsigned short* __restrict__ h,
                                                      const float* __restrict__ AB,
                                                      unsigned short* __restrict__ hc) {
    int i8 = blockIdx.x * blockDim.x + threadIdx.x;
    if (i8 >= N_NODES * 256 / 8) return;
    int n = i8 >> 5;
    int c8 = (i8 & 31) * 8;
    union { int4 v; unsigned short u[8]; } U1, U2;
    U1.v = *(const int4*)(&h[(size_t)n * 512 + c8]);
    U2.v = *(const int4*)(&h[(size_t)n * 512 + 256 + c8]);
    unsigned short os[8];
#pragma unroll
    for (int j = 0; j < 8; j++) {
        int c = c8 + j;
        float y1 = fmaxf(fmaf(bf2f(U1.u[j]), AB[c], AB[512 + c]), 0.0f);
        int c2 = c + 256;
        float y2 = fmaxf(fmaf(bf2f(U2.u[j]), AB[c2], AB[512 + c2]), 0.0f);
        os[j] = f2bf(y1 + y2);
    }
    int4 ov;
    ov.x = (int)(((unsigned)os[1] << 16) | os[0]);
    ov.y = (int)(((unsigned)os[3] << 16) | os[2]);
    ov.z = (int)(((unsigned)os[5] << 16) | os[4]);
    ov.w = (int)(((unsigned)os[7] << 16) | os[6]);
    *(int4*)(&hc[(size_t)i8 * 8]) = ov;
}

// ---------------- edge MLP layer 1 ----------------
__global__ __launch_bounds__(256) void edge_l1(const unsigned short* __restrict__ PQ,
                                               const int* __restrict__ src,
                                               const int* __restrict__ dst,
                                               const float* __restrict__ ea,
                                               const float* __restrict__ Wc1e,
                                               const float* __restrict__ bc1,
                                               unsigned short* __restrict__ e1out,
                                               int e_base, int count) {
    int wid = threadIdx.x >> 6, l = threadIdx.x & 63;
    int el = blockIdx.x * 4 + wid;
    if (el >= count) return;
    int e = e_base + el;
    int s = src[e], d = dst[e];
    int c0 = l * 4;
    union { int2 v; unsigned short u[4]; } Pu, Qu;
    Pu.v = *(const int2*)(&PQ[(size_t)s * 512 + c0]);
    Qu.v = *(const int2*)(&PQ[(size_t)d * 512 + 256 + c0]);
    float v[4];
#pragma unroll
    for (int j = 0; j < 4; j++) v[j] = bf2f(Pu.u[j]) + bf2f(Qu.u[j]) + bc1[c0 + j];
#pragma unroll
    for (int jj = 0; jj < 8; jj++) {
        float av = ea[(size_t)e * 8 + jj];
        float4 w = *(const float4*)(&Wc1e[jj * 256 + c0]);
        v[0] += av * w.x; v[1] += av * w.y; v[2] += av * w.z; v[3] += av * w.w;
    }
    unsigned short os[4];
#pragma unroll
    for (int j = 0; j < 4; j++) os[j] = f2bf(fmaxf(v[j], 0.0f));
    *(uint2*)(&e1out[(size_t)el * 256 + c0]) =
        make_uint2(((unsigned)os[1] << 16) | os[0], ((unsigned)os[3] << 16) | os[2]);
}

// ---------------- launch ----------------
extern "C" void kernel_launch(void* const* d_in, const int* in_sizes, int n_in,
                              void* d_out, int out_size, void* d_ws, size_t ws_size,
                              hipStream_t stream) {
    const float* x   = (const float*)d_in[0];
    const int*   ei  = (const int*)d_in[1];
    const float* ea  = (const float*)d_in[2];
    const float* W11 = (const float*)d_in[3];
    const float* b11 = (const float*)d_in[4];
    const float* W12 = (const float*)d_in[5];
    const float* b12 = (const float*)d_in[6];
    const float* W13 = (const float*)d_in[7];
    const float* b13 = (const float*)d_in[8];
    const float* W21 = (const float*)d_in[9];
    const float* b21 = (const float*)d_in[10];
    const float* W22 = (const float*)d_in[11];
    const float* b22 = (const float*)d_in[12];
    const float* W23 = (const float*)d_in[13];
    const float* b23 = (const float*)d_in[14];
    const float* g1  = (const float*)d_in[15];
    const float* be1 = (const float*)d_in[16];
    const float* g2  = (const float*)d_in[17];
    const float* be2 = (const float*)d_in[18];
    const float* g3  = (const float*)d_in[19];
    const float* be3 = (const float*)d_in[20];
    const float* Wc1 = (const float*)d_in[21];
    const float* bc1 = (const float*)d_in[22];
    const float* Wc2 = (const float*)d_in[23];
    const float* bc2 = (const float*)d_in[24];
    const float* Wc3 = (const float*)d_in[25];
    const float* bc3 = (const float*)d_in[26];
    const float* Wc4 = (const float*)d_in[27];
    const float* bc4 = (const float*)d_in[28];
    const float* Wc5 = (const float*)d_in[29];
    const float* bc5 = (const float*)d_in[30];

    const int* src = ei;
    const int* dst = ei + N_EDGES;
    float* out = (float*)d_out;

    // ---- workspace carve ----
    char* w = (char*)d_ws;
    auto alloc = [&](size_t bytes) {
        char* p = w;
        w += (bytes + 255) & ~(size_t)255;
        return p;
    };
    float* isd     = (float*)alloc(N_NODES * 4);
    int2*  pk      = (int2*)alloc((size_t)N_EDGES * 8);
    int*   counts  = (int*)alloc((N_NODES + 4) * 4);
    int*   offsets = (int*)alloc((N_NODES + 4) * 4);
    int*   bsum    = (int*)alloc(256 * 4);
    int*   boff    = (int*)alloc(256 * 4);
    float* stats   = (float*)alloc(1024 * 4);
    float* AB      = (float*)alloc(1024 * 4);
    unsigned short* W11t = (unsigned short*)alloc(256 * 128 * 2);
    unsigned short* W21t = (unsigned short*)alloc(256 * 128 * 2);
    unsigned short* W12t = (unsigned short*)alloc(256 * 256 * 2);
    unsigned short* W22t = (unsigned short*)alloc(256 * 256 * 2);
    unsigned short* W13t = (unsigned short*)alloc(256 * 256 * 2);
    unsigned short* W23t = (unsigned short*)alloc(256 * 256 * 2);
    unsigned short* WPQt = (unsigned short*)alloc(512 * 256 * 2);
    unsigned short* Wc2t = (unsigned short*)alloc(256 * 256 * 2);
    unsigned short* Wc3t = (unsigned short*)alloc(128 * 256 * 2);
    unsigned short* Wc4t = (unsigned short*)alloc(64 * 128 * 2);
    unsigned short* xb   = (unsigned short*)alloc((size_t)N_NODES * 128 * 2);
    unsigned short* hb   = (unsigned short*)alloc((size_t)N_NODES * 512 * 2);
    unsigned short* hwb  = (unsigned short*)alloc((size_t)N_NODES * 512 * 2);
    unsigned short* hagg = (unsigned short*)alloc((size_t)N_NODES * 512 * 2);
    unsigned short* hc   = (unsigned short*)alloc((size_t)N_NODES * 256 * 2);
    (void)ws_size;

    // edge-phase aliases (dead regions): e1 <- hagg, e2 <- xb+hb, e3 <- hagg
    unsigned short* e1 = hagg;
    unsigned short* e2 = xb;
    unsigned short* e3 = hagg;

    // ---- CSR build ----
    zero_i32<<<(N_NODES + 256) / 256, 256, 0, stream>>>(counts, N_NODES + 1);
    count_deg<<<(N_EDGES + 255) / 256, 256, 0, stream>>>(dst, counts);
    isd_kernel<<<(N_NODES + 255) / 256, 256, 0, stream>>>(counts, isd);
    scan_reduce<<<NB_SCAN, 256, 0, stream>>>(counts, bsum);
    scan_tops<<<1, 256, 0, stream>>>(bsum, boff, NB_SCAN, offsets + N_NODES);
    scan_final<<<NB_SCAN, 256, 0, stream>>>(counts, boff, offsets);
    zero_i32<<<(N_NODES + 255) / 256, 256, 0, stream>>>(counts, N_NODES);
    fill_csr<<<(N_EDGES + 255) / 256, 256, 0, stream>>>(src, dst, isd, offsets, counts, pk);

    // ---- preconvert ----
    conv_f32_bf16<<<(N_NODES * 128 / 4 + 255) / 256, 256, 0, stream>>>(x, xb,
                                                                        N_NODES * 128 / 4);
    auto tr = [&](const float* W, unsigned short* Wt, int K, int Nout) {
        transp_conv<<<(K * Nout + 255) / 256, 256, 0, stream>>>(W, Wt, K, Nout);
    };
    tr(W11, W11t, 128, 256); tr(W21, W21t, 128, 256);
    tr(W12, W12t, 256, 256); tr(W22, W22t, 256, 256);
    tr(W13, W13t, 256, 256); tr(W23, W23t, 256, 256);
    tr(Wc1, WPQt, 256, 256);
    tr(Wc1 + 256 * 256, WPQt + 256 * 256, 256, 256);
    tr(Wc2, Wc2t, 256, 256);
    tr(Wc3, Wc3t, 256, 128);
    tr(Wc4, Wc4t, 128, 64);

    // ---- 3 GCN layers (dual-branch GEMM in one dispatch) ----
    const unsigned short* Wat[3] = {W11t, W12t, W13t};
    const unsigned short* Wbt[3] = {W21t, W22t, W23t};
    const float* ba[3] = {b11, b12, b13};
    const float* bb[3] = {b21, b22, b23};
    const float* gs[3] = {g1, g2, g3};
    const float* bes[3] = {be1, be2, be3};

    int gx_n = (N_NODES + 127) / 128;  // 391
    for (int l = 0; l < 3; l++) {
        if (l == 0) {
            gemm_mfma<128, 1, 0, 0, 1><<<dim3(gx_n, 4), 256, 0, stream>>>(
                xb, 128, Wat[0], nullptr, hwb, 512, N_NODES, 128, nullptr, nullptr,
                xb, Wbt[0]);
        } else {
            gemm_mfma<128, 1, 0, 0, 1><<<dim3(gx_n, 4), 256, 0, stream>>>(
                hb, 512, Wat[l], nullptr, hwb, 512, N_NODES, 256, nullptr, nullptr,
                hb + 256, Wbt[l]);
        }
        aggregate2<<<N_NODES / 4, 256, 0, stream>>>(hwb, isd, offsets, pk,
                                                    ba[l], bb[l], hagg);
        zero_f32<<<4, 256, 0, stream>>>(stats, 1024);
        bn_stats2<<<STAT_BLOCKS, 256, 0, stream>>>(hagg, stats);
        bn_ab<<<1, 256, 0, stream>>>(stats, gs[l], bes[l], AB);
        if (l < 2) {
            bn_apply<<<(N_NODES * 512 / 8 + 255) / 256, 256, 0, stream>>>(hagg, AB, hb);
        } else {
            bn_apply_final<<<(N_NODES * 256 / 8 + 255) / 256, 256, 0, stream>>>(hagg, AB, hc);
        }
    }

    // ---- PQ = hc @ [Wc1_P | Wc1_Q] -> hwb [N][512] bf16 ----
    gemm_mfma<128, 1, 0, 0, 0><<<dim3(gx_n, 4), 256, 0, stream>>>(hc, 256, WPQt, nullptr,
                                                                  hwb, 512, N_NODES, 256,
                                                                  nullptr, nullptr,
                                                                  nullptr, nullptr);

    // ---- edge MLP in chunks ----
    int gx_e = (CHUNK + 127) / 128;  // 782
    for (int c0 = 0; c0 < N_EDGES; c0 += CHUNK) {
        int cnt = CHUNK;
        edge_l1<<<(cnt + 3) / 4, 256, 0, stream>>>(hwb, src, dst, ea, Wc1 + 512 * 256, bc1,
                                                   e1, c0, cnt);
        gemm_mfma<128, 1, 1, 1, 0><<<dim3(gx_e, 2), 256, 0, stream>>>(
            e1, 256, Wc2t, bc2, e2, 256, cnt, 256, nullptr, nullptr, nullptr, nullptr);
        gemm_mfma<128, 1, 1, 1, 0><<<dim3(gx_e, 1), 256, 0, stream>>>(
            e2, 256, Wc3t, bc3, e3, 128, cnt, 256, nullptr, nullptr, nullptr, nullptr);
        gemm_mfma<64, 2, 1, 1, 0><<<dim3(gx_e, 1), 256, 0, stream>>>(
            e3, 128, Wc4t, bc4, out + (size_t)c0 * 2, 0, cnt, 128, Wc5, bc5,
            nullptr, nullptr);
    }
}

// Round 6
// 898.282 us; speedup vs baseline: 3.6589x; 1.1952x over previous
//
#include <hip/hip_runtime.h>

#define N_NODES 50000
#define N_EDGES 400000
#define EPB     128          // edges per block in fused edge MLP
#define NB_SCAN 196
#define BN_EPS  1e-5f
#define STAT_BLOCKS 128

typedef __attribute__((ext_vector_type(8))) short s16x8;
typedef __attribute__((ext_vector_type(4))) float f32x4;

__device__ __forceinline__ unsigned short f2bf(float x) {
    unsigned u = __float_as_uint(x);
    return (unsigned short)((u + 0x7fffu + ((u >> 16) & 1u)) >> 16);
}
__device__ __forceinline__ float bf2f(unsigned short b) {
    return __uint_as_float(((unsigned)b) << 16);
}

// direct global->LDS 16B load (linear LDS dest = wave base + lane*16)
__device__ __forceinline__ void gload_lds16(const void* g, void* lds) {
    auto gp = reinterpret_cast<const __attribute__((address_space(1))) unsigned int*>(
        reinterpret_cast<uintptr_t>(g));
    auto lp = reinterpret_cast<__attribute__((address_space(3))) unsigned int*>(
        reinterpret_cast<uintptr_t>(lds));
    __builtin_amdgcn_global_load_lds(gp, lp, 16, 0, 0);
}

// ---------------- utility ----------------
__global__ void zero_i32(int* p, int n) {
    int i = blockIdx.x * blockDim.x + threadIdx.x;
    if (i < n) p[i] = 0;
}
__global__ void zero_f32(float* p, int n) {
    int i = blockIdx.x * blockDim.x + threadIdx.x;
    if (i < n) p[i] = 0.0f;
}
__global__ void count_deg(const int* __restrict__ dst, int* __restrict__ counts) {
    int e = blockIdx.x * blockDim.x + threadIdx.x;
    if (e < N_EDGES) atomicAdd(&counts[dst[e]], 1);
}
__global__ void isd_kernel(const int* __restrict__ counts, float* __restrict__ isd) {
    int i = blockIdx.x * blockDim.x + threadIdx.x;
    if (i < N_NODES) isd[i] = rsqrtf(1.0f + (float)counts[i]);
}

// ---------------- 3-phase scan ----------------
__global__ __launch_bounds__(256) void scan_reduce(const int* __restrict__ counts,
                                                   int* __restrict__ bsum) {
    __shared__ int sh[256];
    int t = threadIdx.x, b = blockIdx.x;
    int i = b * 256 + t;
    sh[t] = (i < N_NODES) ? counts[i] : 0;
    __syncthreads();
    for (int o = 128; o > 0; o >>= 1) {
        if (t < o) sh[t] += sh[t + o];
        __syncthreads();
    }
    if (t == 0) bsum[b] = sh[0];
}
__global__ __launch_bounds__(256) void scan_tops(const int* __restrict__ bsum,
                                                 int* __restrict__ boff, int nb,
                                                 int* __restrict__ total_out) {
    __shared__ int sh[256];
    int t = threadIdx.x;
    int v = (t < nb) ? bsum[t] : 0;
    sh[t] = v;
    __syncthreads();
    for (int o = 1; o < 256; o <<= 1) {
        int a = (t >= o) ? sh[t - o] : 0;
        __syncthreads();
        sh[t] += a;
        __syncthreads();
    }
    if (t < nb) boff[t] = sh[t] - v;
    if (t == 255) *total_out = sh[255];
}
__global__ __launch_bounds__(256) void scan_final(const int* __restrict__ counts,
                                                  const int* __restrict__ boff,
                                                  int* __restrict__ offsets) {
    __shared__ int sh[256];
    int t = threadIdx.x, b = blockIdx.x;
    int i = b * 256 + t;
    int v = (i < N_NODES) ? counts[i] : 0;
    sh[t] = v;
    __syncthreads();
    for (int o = 1; o < 256; o <<= 1) {
        int a = (t >= o) ? sh[t - o] : 0;
        __syncthreads();
        sh[t] += a;
        __syncthreads();
    }
    if (i < N_NODES) offsets[i] = boff[b] + sh[t] - v;
}

// packed CSR entry: (src, norm) as int2; also dst and orig-edge-id per CSR slot
__global__ void fill_csr(const int* __restrict__ src, const int* __restrict__ dst,
                         const float* __restrict__ isd, const int* __restrict__ offsets,
                         int* __restrict__ cursor, int2* __restrict__ pk,
                         int* __restrict__ edstA, int* __restrict__ eorigA) {
    int e = blockIdx.x * blockDim.x + threadIdx.x;
    if (e >= N_EDGES) return;
    int s = src[e], d = dst[e];
    int pos = offsets[d] + atomicAdd(&cursor[d], 1);
    pk[pos] = make_int2(s, __float_as_int(isd[s] * isd[d]));
    edstA[pos] = d;
    eorigA[pos] = e;
}

// ---------------- conversions ----------------
__global__ void conv_f32_bf16(const float* __restrict__ in, unsigned short* __restrict__ out,
                              int n4) {
    int i = blockIdx.x * blockDim.x + threadIdx.x;
    if (i >= n4) return;
    float4 v = ((const float4*)in)[i];
    unsigned short o0 = f2bf(v.x), o1 = f2bf(v.y), o2 = f2bf(v.z), o3 = f2bf(v.w);
    ((uint2*)out)[i] = make_uint2(((unsigned)o1 << 16) | o0, ((unsigned)o3 << 16) | o2);
}

__global__ void transp_conv(const float* __restrict__ W, unsigned short* __restrict__ Wt,
                            int K, int Nout) {
    int idx = blockIdx.x * blockDim.x + threadIdx.x;
    if (idx >= K * Nout) return;
    int k = idx / Nout, n = idx % Nout;
    Wt[(size_t)n * K + k] = f2bf(W[idx]);
}

// ---------------- bf16 MFMA GEMM (global_load_lds staging) ----------------
// C[M][Nout] = A[M][K] @ Wt[Nout][K]^T. OUT_MODE: 0=f32, 1=bf16.
// DUAL: grid.y=4, half=(y>>1) selects {A,Wt} vs {A2,Wt2}, output col offset half*256.
template <int BN_T, int OUT_MODE, int RELU, int BIAS, int DUAL>
__global__ __launch_bounds__(256) void gemm_mfma(const unsigned short* __restrict__ A, int lda,
                                                 const unsigned short* __restrict__ Wt,
                                                 const float* __restrict__ bias,
                                                 void* __restrict__ Cout, int ldc,
                                                 int M, int K,
                                                 const unsigned short* __restrict__ A2,
                                                 const unsigned short* __restrict__ Wt2) {
    constexpr int MI = (BN_T == 128) ? 4 : 2;
    constexpr int NI = 4;
    __shared__ __align__(16) short As[128 * 32];
    __shared__ __align__(16) short Bs[BN_T * 32];

    const int tid = threadIdx.x;
    const int l = tid & 63;
    const int wv = tid >> 6;
    const int wrow = (BN_T == 128) ? (wv >> 1) * 64 : wv * 32;
    const int wcol = (BN_T == 128) ? (wv & 1) * 64 : 0;
    const int bm = blockIdx.x * 128;
    int bn, coloff;
    const unsigned short* Ause;
    const unsigned short* Wuse;
    if (DUAL) {
        int half_ = blockIdx.y >> 1;
        bn = (blockIdx.y & 1) * BN_T;
        coloff = half_ * 256;
        Ause = half_ ? A2 : A;
        Wuse = half_ ? Wt2 : Wt;
    } else {
        bn = blockIdx.y * BN_T;
        coloff = 0;
        Ause = A;
        Wuse = Wt;
    }
    const int rsub = l >> 2;
    const int gl = l & 3;

    f32x4 acc[MI][NI] = {};

    for (int k0 = 0; k0 < K; k0 += 32) {
#pragma unroll
        for (int i = 0; i < 2; i++) {
            int lr = wv * 32 + i * 16 + rsub;
            int gr = bm + lr;
            if (gr >= M) gr = M - 1;
            int gsrc = gl ^ ((lr >> 1) & 3);
            gload_lds16(&Ause[(size_t)gr * lda + k0 + gsrc * 8],
                        &As[(wv * 32 + i * 16) * 32]);
        }
#pragma unroll
        for (int i = 0; i < BN_T / 64; i++) {
            int base = (BN_T == 128) ? (wv * 32 + i * 16) : (wv * 16);
            int lr = base + rsub;
            int gsrc = gl ^ ((lr >> 1) & 3);
            gload_lds16(&Wuse[(size_t)(bn + lr) * K + k0 + gsrc * 8],
                        &Bs[base * 32]);
        }
        __syncthreads();

        s16x8 af[MI], bfr[NI];
        const int q = l >> 4;
#pragma unroll
        for (int mi = 0; mi < MI; mi++) {
            int r = wrow + mi * 16 + (l & 15);
            af[mi] = *(const s16x8*)(&As[r * 32 + ((q ^ ((r >> 1) & 3)) << 3)]);
        }
#pragma unroll
        for (int ni = 0; ni < NI; ni++) {
            int r = wcol + ni * 16 + (l & 15);
            bfr[ni] = *(const s16x8*)(&Bs[r * 32 + ((q ^ ((r >> 1) & 3)) << 3)]);
        }
#pragma unroll
        for (int mi = 0; mi < MI; mi++)
#pragma unroll
            for (int ni = 0; ni < NI; ni++)
                acc[mi][ni] = __builtin_amdgcn_mfma_f32_16x16x32_bf16(af[mi], bfr[ni],
                                                                      acc[mi][ni], 0, 0, 0);
        __syncthreads();
    }

#pragma unroll
    for (int mi = 0; mi < MI; mi++) {
#pragma unroll
        for (int ni = 0; ni < NI; ni++) {
            int colB = coloff + bn + wcol + ni * 16 + (l & 15);
            float bv = BIAS ? bias[colB] : 0.0f;
#pragma unroll
            for (int r = 0; r < 4; r++) {
                int row = bm + wrow + mi * 16 + (l >> 4) * 4 + r;
                if (row < M) {
                    float v = acc[mi][ni][r] + bv;
                    if (RELU) v = fmaxf(v, 0.0f);
                    if (OUT_MODE == 1)
                        ((unsigned short*)Cout)[(size_t)row * ldc + colB] = f2bf(v);
                    else
                        ((float*)Cout)[(size_t)row * ldc + colB] = v;
                }
            }
        }
    }
}

// ---------------- fused edge MLP megakernel ----------------
// Per block: 128 CSR-ordered edges. Phase0: gather layer-1 into LDS A-tile.
// Then 3 chained GEMMs entirely in LDS, fused Wc5 output, scatter by eorig.
__global__ __launch_bounds__(256, 2) void edge_mlp_fused(
    const unsigned short* __restrict__ PQ, const int2* __restrict__ pk,
    const int* __restrict__ edstA, const int* __restrict__ eorigA,
    const float* __restrict__ ea, const float* __restrict__ Wc1e,
    const float* __restrict__ bc1,
    const unsigned short* __restrict__ Wc2t, const float* __restrict__ bc2,
    const unsigned short* __restrict__ Wc3t, const float* __restrict__ bc3,
    const unsigned short* __restrict__ Wc4t, const float* __restrict__ bc4,
    const float* __restrict__ Wc5, const float* __restrict__ bc5,
    float* __restrict__ out) {
    __shared__ __align__(16) short At[EPB * 256];  // 64KB, swizzled [row][ch]
    __shared__ __align__(16) short Bs[256 * 32];   // 16KB weight staging

    const int tid = threadIdx.x;
    const int l = tid & 63;
    const int wv = tid >> 6;
    const int p0 = blockIdx.x * EPB;
    const int lm = l & 15;
    const int q = l >> 4;
    const int rsub = l >> 2;
    const int gl = l & 3;

    // ---- phase 0: gather + edge layer 1 -> At (row=edge, ch=0..255) ----
    {
        const int c0 = l * 4;
        float bi0 = bc1[c0], bi1 = bc1[c0 + 1], bi2 = bc1[c0 + 2], bi3 = bc1[c0 + 3];
        float4 w8[8];
#pragma unroll
        for (int jj = 0; jj < 8; jj++) w8[jj] = *(const float4*)(&Wc1e[jj * 256 + c0]);
        const int g = l >> 1;
        const int sub = (l & 1) * 4;
        for (int i = 0; i < 32; i++) {
            int row = wv * 32 + i;
            int p = p0 + row;
            int s = pk[p].x;
            int d = edstA[p];
            int eo = eorigA[p];
            union { int2 v; unsigned short u[4]; } Pu, Qu;
            Pu.v = *(const int2*)(&PQ[(size_t)s * 512 + c0]);
            Qu.v = *(const int2*)(&PQ[(size_t)d * 512 + 256 + c0]);
            float v0 = bf2f(Pu.u[0]) + bf2f(Qu.u[0]) + bi0;
            float v1 = bf2f(Pu.u[1]) + bf2f(Qu.u[1]) + bi1;
            float v2 = bf2f(Pu.u[2]) + bf2f(Qu.u[2]) + bi2;
            float v3 = bf2f(Pu.u[3]) + bf2f(Qu.u[3]) + bi3;
#pragma unroll
            for (int jj = 0; jj < 8; jj++) {
                float av = ea[(size_t)eo * 8 + jj];
                v0 = fmaf(av, w8[jj].x, v0);
                v1 = fmaf(av, w8[jj].y, v1);
                v2 = fmaf(av, w8[jj].z, v2);
                v3 = fmaf(av, w8[jj].w, v3);
            }
            unsigned short o0 = f2bf(fmaxf(v0, 0.0f)), o1 = f2bf(fmaxf(v1, 0.0f));
            unsigned short o2 = f2bf(fmaxf(v2, 0.0f)), o3 = f2bf(fmaxf(v3, 0.0f));
            int off = row * 256 + ((g ^ (row & 7)) << 3) + sub;
            *(uint2*)(&At[off]) =
                make_uint2(((unsigned)o1 << 16) | o0, ((unsigned)o3 << 16) | o2);
        }
    }
    __syncthreads();

    // ---- GEMM1: [128x256] = relu(At @ Wc2t^T + bc2) -> At ----
    {
        const int wrow = (wv >> 1) * 64;
        const int wcol = (wv & 1) * 128;
        f32x4 acc[4][8] = {};
        for (int k0 = 0; k0 < 256; k0 += 32) {
#pragma unroll
            for (int i = 0; i < 4; i++) {
                int lr = wv * 64 + i * 16 + rsub;
                int gsrc = gl ^ ((lr >> 1) & 3);
                gload_lds16(&Wc2t[(size_t)lr * 256 + k0 + gsrc * 8],
                            &Bs[(wv * 64 + i * 16) * 32]);
            }
            __syncthreads();
            s16x8 af[4], bfr[8];
#pragma unroll
            for (int mi = 0; mi < 4; mi++) {
                int r = wrow + mi * 16 + lm;
                int G = (k0 >> 3) + q;
                af[mi] = *(const s16x8*)(&At[r * 256 + ((G ^ (r & 7)) << 3)]);
            }
#pragma unroll
            for (int ni = 0; ni < 8; ni++) {
                int rb = wcol + ni * 16 + lm;
                bfr[ni] = *(const s16x8*)(&Bs[rb * 32 + ((q ^ ((rb >> 1) & 3)) << 3)]);
            }
#pragma unroll
            for (int mi = 0; mi < 4; mi++)
#pragma unroll
                for (int ni = 0; ni < 8; ni++)
                    acc[mi][ni] = __builtin_amdgcn_mfma_f32_16x16x32_bf16(
                        af[mi], bfr[ni], acc[mi][ni], 0, 0, 0);
            __syncthreads();
        }
        // epilogue back into At (all A1 reads complete after final barrier)
#pragma unroll
        for (int mi = 0; mi < 4; mi++) {
#pragma unroll
            for (int ni = 0; ni < 8; ni++) {
                int col = wcol + ni * 16 + lm;
                float bv = bc2[col];
#pragma unroll
                for (int r = 0; r < 4; r++) {
                    int row = wrow + mi * 16 + q * 4 + r;
                    At[row * 256 + (((col >> 3) ^ (row & 7)) << 3) + (col & 7)] =
                        (short)f2bf(fmaxf(acc[mi][ni][r] + bv, 0.0f));
                }
            }
        }
    }
    __syncthreads();

    // ---- GEMM2: [128x128] = relu(A2 @ Wc3t^T + bc3) -> At (stride 128) ----
    {
        const int wrow = (wv >> 1) * 64;
        const int wcol = (wv & 1) * 64;
        f32x4 acc[4][4] = {};
        for (int k0 = 0; k0 < 256; k0 += 32) {
#pragma unroll
            for (int i = 0; i < 2; i++) {
                int lr = wv * 32 + i * 16 + rsub;
                int gsrc = gl ^ ((lr >> 1) & 3);
                gload_lds16(&Wc3t[(size_t)lr * 256 + k0 + gsrc * 8],
                            &Bs[(wv * 32 + i * 16) * 32]);
            }
            __syncthreads();
            s16x8 af[4], bfr[4];
#pragma unroll
            for (int mi = 0; mi < 4; mi++) {
                int r = wrow + mi * 16 + lm;
                int G = (k0 >> 3) + q;
                af[mi] = *(const s16x8*)(&At[r * 256 + ((G ^ (r & 7)) << 3)]);
            }
#pragma unroll
            for (int ni = 0; ni < 4; ni++) {
                int rb = wcol + ni * 16 + lm;
                bfr[ni] = *(const s16x8*)(&Bs[rb * 32 + ((q ^ ((rb >> 1) & 3)) << 3)]);
            }
#pragma unroll
            for (int mi = 0; mi < 4; mi++)
#pragma unroll
                for (int ni = 0; ni < 4; ni++)
                    acc[mi][ni] = __builtin_amdgcn_mfma_f32_16x16x32_bf16(
                        af[mi], bfr[ni], acc[mi][ni], 0, 0, 0);
            __syncthreads();
        }
#pragma unroll
        for (int mi = 0; mi < 4; mi++) {
#pragma unroll
            for (int ni = 0; ni < 4; ni++) {
                int col = wcol + ni * 16 + lm;
                float bv = bc3[col];
#pragma unroll
                for (int r = 0; r < 4; r++) {
                    int row = wrow + mi * 16 + q * 4 + r;
                    At[row * 128 + (((col >> 3) ^ (row & 7)) << 3) + (col & 7)] =
                        (short)f2bf(fmaxf(acc[mi][ni][r] + bv, 0.0f));
                }
            }
        }
    }
    __syncthreads();

    // ---- GEMM3: [128x64] = A3 @ Wc4t^T, fused relu+bc4 then @Wc5 + bc5, scatter ----
    {
        const int wrow = wv * 32;
        f32x4 acc[2][4] = {};
        for (int k0 = 0; k0 < 128; k0 += 32) {
            {
                int lr = wv * 16 + rsub;
                int gsrc = gl ^ ((lr >> 1) & 3);
                gload_lds16(&Wc4t[(size_t)lr * 128 + k0 + gsrc * 8],
                            &Bs[(wv * 16) * 32]);
            }
            __syncthreads();
            s16x8 af[2], bfr[4];
#pragma unroll
            for (int mi = 0; mi < 2; mi++) {
                int r = wrow + mi * 16 + lm;
                int G = (k0 >> 3) + q;
                af[mi] = *(const s16x8*)(&At[r * 128 + ((G ^ (r & 7)) << 3)]);
            }
#pragma unroll
            for (int ni = 0; ni < 4; ni++) {
                int rb = ni * 16 + lm;
                bfr[ni] = *(const s16x8*)(&Bs[rb * 32 + ((q ^ ((rb >> 1) & 3)) << 3)]);
            }
#pragma unroll
            for (int mi = 0; mi < 2; mi++)
#pragma unroll
                for (int ni = 0; ni < 4; ni++)
                    acc[mi][ni] = __builtin_amdgcn_mfma_f32_16x16x32_bf16(
                        af[mi], bfr[ni], acc[mi][ni], 0, 0, 0);
            __syncthreads();
        }
#pragma unroll
        for (int mi = 0; mi < 2; mi++) {
#pragma unroll
            for (int r = 0; r < 4; r++) {
                float pa = 0.f, pb = 0.f;
#pragma unroll
                for (int ni = 0; ni < 4; ni++) {
                    int col = ni * 16 + lm;
                    float v = fmaxf(acc[mi][ni][r] + bc4[col], 0.0f);
                    pa = fmaf(v, Wc5[col * 2 + 0], pa);
                    pb = fmaf(v, Wc5[col * 2 + 1], pb);
                }
#pragma unroll
                for (int o = 1; o < 16; o <<= 1) {
                    pa += __shfl_xor(pa, o, 64);
                    pb += __shfl_xor(pb, o, 64);
                }
                if (lm == 0) {
                    int row = wrow + mi * 16 + q * 4 + r;
                    int eo = eorigA[p0 + row];
                    out[(size_t)eo * 2 + 0] = pa + bc5[0];
                    out[(size_t)eo * 2 + 1] = pb + bc5[1];
                }
            }
        }
    }
}

// ---------------- GCN aggregation: 1 node/wave, packed pairs, bf16 out ----------------
__global__ __launch_bounds__(256) void aggregate2(const unsigned short* __restrict__ hwb,
                                                  const float* __restrict__ isd,
                                                  const int* __restrict__ offsets,
                                                  const int2* __restrict__ pk,
                                                  const float* __restrict__ b1,
                                                  const float* __restrict__ b2,
                                                  unsigned short* __restrict__ hagg) {
    int wv = threadIdx.x >> 6, l = threadIdx.x & 63;
    int n = blockIdx.x * 4 + wv;
    int c0 = l * 8;
    float acc[8] = {};
    int e0 = offsets[n], e1 = offsets[n + 1];
    int k = e0;
    for (; k + 2 <= e1; k += 2) {
        int2 p0 = pk[k], p1 = pk[k + 1];
        union { int4 v; unsigned short u[8]; } U0, U1;
        U0.v = *(const int4*)(&hwb[(size_t)p0.x * 512 + c0]);
        U1.v = *(const int4*)(&hwb[(size_t)p1.x * 512 + c0]);
        float w0 = __int_as_float(p0.y), w1 = __int_as_float(p1.y);
#pragma unroll
        for (int j = 0; j < 8; j++)
            acc[j] = fmaf(w0, bf2f(U0.u[j]), fmaf(w1, bf2f(U1.u[j]), acc[j]));
    }
    if (k < e1) {
        int2 p0 = pk[k];
        union { int4 v; unsigned short u[8]; } U0;
        U0.v = *(const int4*)(&hwb[(size_t)p0.x * 512 + c0]);
        float w0 = __int_as_float(p0.y);
#pragma unroll
        for (int j = 0; j < 8; j++) acc[j] = fmaf(w0, bf2f(U0.u[j]), acc[j]);
    }
    float si = isd[n]; si *= si;
    union { int4 v; unsigned short u[8]; } U;
    U.v = *(const int4*)(&hwb[(size_t)n * 512 + c0]);
    const float* bp = (c0 < 256) ? (b1 + c0) : (b2 + (c0 - 256));
    unsigned short os[8];
#pragma unroll
    for (int j = 0; j < 8; j++) {
        acc[j] = fmaf(si, bf2f(U.u[j]), acc[j]) + bp[j];
        os[j] = f2bf(acc[j]);
    }
    int4 ov;
    ov.x = (int)(((unsigned)os[1] << 16) | os[0]);
    ov.y = (int)(((unsigned)os[3] << 16) | os[2]);
    ov.z = (int)(((unsigned)os[5] << 16) | os[4]);
    ov.w = (int)(((unsigned)os[7] << 16) | os[6]);
    *(int4*)(&hagg[(size_t)n * 512 + c0]) = ov;
}

// ---------------- BN stats over bf16 [N][512] ----------------
__global__ __launch_bounds__(256) void bn_stats2(const unsigned short* __restrict__ h,
                                                 float* __restrict__ stats) {
    __shared__ float sh[4][1024];
    int t = threadIdx.x;
    int wv = t >> 6, l = t & 63;
    int c0 = l * 8;
    float s[8] = {}, q[8] = {};
    for (int n = blockIdx.x * 4 + wv; n < N_NODES; n += STAT_BLOCKS * 4) {
        union { int4 v; unsigned short u[8]; } U;
        U.v = *(const int4*)(&h[(size_t)n * 512 + c0]);
#pragma unroll
        for (int j = 0; j < 8; j++) {
            float x = bf2f(U.u[j]);
            s[j] += x;
            q[j] = fmaf(x, x, q[j]);
        }
    }
#pragma unroll
    for (int j = 0; j < 8; j++) {
        sh[wv][c0 + j] = s[j];
        sh[wv][512 + c0 + j] = q[j];
    }
    __syncthreads();
    for (int i = t; i < 1024; i += 256) {
        float a = sh[0][i] + sh[1][i] + sh[2][i] + sh[3][i];
        atomicAdd(&stats[i], a);
    }
}

// stats -> per-channel affine AB: y = x*AB[c] + AB[512+c]
__global__ __launch_bounds__(256) void bn_ab(const float* __restrict__ stats,
                                             const float* __restrict__ g,
                                             const float* __restrict__ be,
                                             float* __restrict__ AB) {
    int t = threadIdx.x;
#pragma unroll
    for (int h = 0; h < 2; h++) {
        int c = t + h * 256;
        float m = stats[c] * (1.0f / N_NODES);
        float var = stats[512 + c] * (1.0f / N_NODES) - m * m;
        float sc = g[c & 255] * rsqrtf(var + BN_EPS);
        AB[c] = sc;
        AB[512 + c] = be[c & 255] - m * sc;
    }
}

// y = relu(x*A + B), bf16 in/out, 512-wide
__global__ __launch_bounds__(256) void bn_apply(const unsigned short* __restrict__ h,
                                                const float* __restrict__ AB,
                                                unsigned short* __restrict__ outp) {
    int i8 = blockIdx.x * blockDim.x + threadIdx.x;
    if (i8 >= N_NODES * 512 / 8) return;
    int c8 = (i8 & 63) * 8;
    union { int4 v; unsigned short u[8]; } U;
    U.v = *(const int4*)(&h[(size_t)i8 * 8]);
    unsigned short os[8];
#pragma unroll
    for (int j = 0; j < 8; j++) {
        int c = c8 + j;
        float y = fmaf(bf2f(U.u[j]), AB[c], AB[512 + c]);
        os[j] = f2bf(fmaxf(y, 0.0f));
    }
    int4 ov;
    ov.x = (int)(((unsigned)os[1] << 16) | os[0]);
    ov.y = (int)(((unsigned)os[3] << 16) | os[2]);
    ov.z = (int)(((unsigned)os[5] << 16) | os[4]);
    ov.w = (int)(((unsigned)os[7] << 16) | os[6]);
    *(int4*)(&outp[(size_t)i8 * 8]) = ov;
}

// final: hc = relu(bn(h1)) + relu(bn(h2)), bf16 out 256-wide
__global__ __launch_bounds__(256) void bn_apply_final(const unsigned short* __restrict__ h,
                                                      const float* __restrict__ AB,
                                                      unsigned short* __restrict__ hc) {
    int i8 = blockIdx.x * blockDim.x + threadIdx.x;
    if (i8 >= N_NODES * 256 / 8) return;
    int n = i8 >> 5;
    int c8 = (i8 & 31) * 8;
    union { int4 v; unsigned short u[8]; } U1, U2;
    U1.v = *(const int4*)(&h[(size_t)n * 512 + c8]);
    U2.v = *(const int4*)(&h[(size_t)n * 512 + 256 + c8]);
    unsigned short os[8];
#pragma unroll
    for (int j = 0; j < 8; j++) {
        int c = c8 + j;
        float y1 = fmaxf(fmaf(bf2f(U1.u[j]), AB[c], AB[512 + c]), 0.0f);
        int c2 = c + 256;
        float y2 = fmaxf(fmaf(bf2f(U2.u[j]), AB[c2], AB[512 + c2]), 0.0f);
        os[j] = f2bf(y1 + y2);
    }
    int4 ov;
    ov.x = (int)(((unsigned)os[1] << 16) | os[0]);
    ov.y = (int)(((unsigned)os[3] << 16) | os[2]);
    ov.z = (int)(((unsigned)os[5] << 16) | os[4]);
    ov.w = (int)(((unsigned)os[7] << 16) | os[6]);
    *(int4*)(&hc[(size_t)i8 * 8]) = ov;
}

// ---------------- launch ----------------
extern "C" void kernel_launch(void* const* d_in, const int* in_sizes, int n_in,
                              void* d_out, int out_size, void* d_ws, size_t ws_size,
                              hipStream_t stream) {
    const float* x   = (const float*)d_in[0];
    const int*   ei  = (const int*)d_in[1];
    const float* ea  = (const float*)d_in[2];
    const float* W11 = (const float*)d_in[3];
    const float* b11 = (const float*)d_in[4];
    const float* W12 = (const float*)d_in[5];
    const float* b12 = (const float*)d_in[6];
    const float* W13 = (const float*)d_in[7];
    const float* b13 = (const float*)d_in[8];
    const float* W21 = (const float*)d_in[9];
    const float* b21 = (const float*)d_in[10];
    const float* W22 = (const float*)d_in[11];
    const float* b22 = (const float*)d_in[12];
    const float* W23 = (const float*)d_in[13];
    const float* b23 = (const float*)d_in[14];
    const float* g1  = (const float*)d_in[15];
    const float* be1 = (const float*)d_in[16];
    const float* g2  = (const float*)d_in[17];
    const float* be2 = (const float*)d_in[18];
    const float* g3  = (const float*)d_in[19];
    const float* be3 = (const float*)d_in[20];
    const float* Wc1 = (const float*)d_in[21];
    const float* bc1 = (const float*)d_in[22];
    const float* Wc2 = (const float*)d_in[23];
    const float* bc2 = (const float*)d_in[24];
    const float* Wc3 = (const float*)d_in[25];
    const float* bc3 = (const float*)d_in[26];
    const float* Wc4 = (const float*)d_in[27];
    const float* bc4 = (const float*)d_in[28];
    const float* Wc5 = (const float*)d_in[29];
    const float* bc5 = (const float*)d_in[30];

    const int* src = ei;
    const int* dst = ei + N_EDGES;
    float* out = (float*)d_out;

    // ---- workspace carve ----
    char* w = (char*)d_ws;
    auto alloc = [&](size_t bytes) {
        char* p = w;
        w += (bytes + 255) & ~(size_t)255;
        return p;
    };
    float* isd     = (float*)alloc(N_NODES * 4);
    int2*  pk      = (int2*)alloc((size_t)N_EDGES * 8);
    int*   edstA   = (int*)alloc((size_t)N_EDGES * 4);
    int*   eorigA  = (int*)alloc((size_t)N_EDGES * 4);
    int*   counts  = (int*)alloc((N_NODES + 4) * 4);
    int*   offsets = (int*)alloc((N_NODES + 4) * 4);
    int*   bsum    = (int*)alloc(256 * 4);
    int*   boff    = (int*)alloc(256 * 4);
    float* stats   = (float*)alloc(1024 * 4);
    float* AB      = (float*)alloc(1024 * 4);
    unsigned short* W11t = (unsigned short*)alloc(256 * 128 * 2);
    unsigned short* W21t = (unsigned short*)alloc(256 * 128 * 2);
    unsigned short* W12t = (unsigned short*)alloc(256 * 256 * 2);
    unsigned short* W22t = (unsigned short*)alloc(256 * 256 * 2);
    unsigned short* W13t = (unsigned short*)alloc(256 * 256 * 2);
    unsigned short* W23t = (unsigned short*)alloc(256 * 256 * 2);
    unsigned short* WPQt = (unsigned short*)alloc(512 * 256 * 2);
    unsigned short* Wc2t = (unsigned short*)alloc(256 * 256 * 2);
    unsigned short* Wc3t = (unsigned short*)alloc(128 * 256 * 2);
    unsigned short* Wc4t = (unsigned short*)alloc(64 * 128 * 2);
    unsigned short* xb   = (unsigned short*)alloc((size_t)N_NODES * 128 * 2);
    unsigned short* hb   = (unsigned short*)alloc((size_t)N_NODES * 512 * 2);
    unsigned short* hwb  = (unsigned short*)alloc((size_t)N_NODES * 512 * 2);
    unsigned short* hagg = (unsigned short*)alloc((size_t)N_NODES * 512 * 2);
    unsigned short* hc   = (unsigned short*)alloc((size_t)N_NODES * 256 * 2);
    (void)ws_size;

    // ---- CSR build ----
    zero_i32<<<(N_NODES + 256) / 256, 256, 0, stream>>>(counts, N_NODES + 1);
    count_deg<<<(N_EDGES + 255) / 256, 256, 0, stream>>>(dst, counts);
    isd_kernel<<<(N_NODES + 255) / 256, 256, 0, stream>>>(counts, isd);
    scan_reduce<<<NB_SCAN, 256, 0, stream>>>(counts, bsum);
    scan_tops<<<1, 256, 0, stream>>>(bsum, boff, NB_SCAN, offsets + N_NODES);
    scan_final<<<NB_SCAN, 256, 0, stream>>>(counts, boff, offsets);
    zero_i32<<<(N_NODES + 255) / 256, 256, 0, stream>>>(counts, N_NODES);
    fill_csr<<<(N_EDGES + 255) / 256, 256, 0, stream>>>(src, dst, isd, offsets, counts,
                                                        pk, edstA, eorigA);

    // ---- preconvert ----
    conv_f32_bf16<<<(N_NODES * 128 / 4 + 255) / 256, 256, 0, stream>>>(x, xb,
                                                                        N_NODES * 128 / 4);
    auto tr = [&](const float* W, unsigned short* Wt, int K, int Nout) {
        transp_conv<<<(K * Nout + 255) / 256, 256, 0, stream>>>(W, Wt, K, Nout);
    };
    tr(W11, W11t, 128, 256); tr(W21, W21t, 128, 256);
    tr(W12, W12t, 256, 256); tr(W22, W22t, 256, 256);
    tr(W13, W13t, 256, 256); tr(W23, W23t, 256, 256);
    tr(Wc1, WPQt, 256, 256);
    tr(Wc1 + 256 * 256, WPQt + 256 * 256, 256, 256);
    tr(Wc2, Wc2t, 256, 256);
    tr(Wc3, Wc3t, 256, 128);
    tr(Wc4, Wc4t, 128, 64);

    // ---- 3 GCN layers (dual-branch GEMM in one dispatch) ----
    const unsigned short* Wat[3] = {W11t, W12t, W13t};
    const unsigned short* Wbt[3] = {W21t, W22t, W23t};
    const float* ba[3] = {b11, b12, b13};
    const float* bb[3] = {b21, b22, b23};
    const float* gs[3] = {g1, g2, g3};
    const float* bes[3] = {be1, be2, be3};

    int gx_n = (N_NODES + 127) / 128;  // 391
    for (int l = 0; l < 3; l++) {
        if (l == 0) {
            gemm_mfma<128, 1, 0, 0, 1><<<dim3(gx_n, 4), 256, 0, stream>>>(
                xb, 128, Wat[0], nullptr, hwb, 512, N_NODES, 128, xb, Wbt[0]);
        } else {
            gemm_mfma<128, 1, 0, 0, 1><<<dim3(gx_n, 4), 256, 0, stream>>>(
                hb, 512, Wat[l], nullptr, hwb, 512, N_NODES, 256, hb + 256, Wbt[l]);
        }
        aggregate2<<<N_NODES / 4, 256, 0, stream>>>(hwb, isd, offsets, pk,
                                                    ba[l], bb[l], hagg);
        zero_f32<<<4, 256, 0, stream>>>(stats, 1024);
        bn_stats2<<<STAT_BLOCKS, 256, 0, stream>>>(hagg, stats);
        bn_ab<<<1, 256, 0, stream>>>(stats, gs[l], bes[l], AB);
        if (l < 2) {
            bn_apply<<<(N_NODES * 512 / 8 + 255) / 256, 256, 0, stream>>>(hagg, AB, hb);
        } else {
            bn_apply_final<<<(N_NODES * 256 / 8 + 255) / 256, 256, 0, stream>>>(hagg, AB, hc);
        }
    }

    // ---- PQ = hc @ [Wc1_P | Wc1_Q] -> hwb [N][512] bf16 ----
    gemm_mfma<128, 1, 0, 0, 0><<<dim3(gx_n, 4), 256, 0, stream>>>(hc, 256, WPQt, nullptr,
                                                                  hwb, 512, N_NODES, 256,
                                                                  nullptr, nullptr);

    // ---- fused edge MLP: one dispatch, all 400K edges ----
    edge_mlp_fused<<<N_EDGES / EPB, 256, 0, stream>>>(
        hwb, pk, edstA, eorigA, ea, Wc1 + 512 * 256, bc1,
        Wc2t, bc2, Wc3t, bc3, Wc4t, bc4, Wc5, bc5, out);
}

// Round 7
// 762.888 us; speedup vs baseline: 4.3083x; 1.1775x over previous
//
#include <hip/hip_runtime.h>

#define N_NODES 50000
#define N_EDGES 400000
#define EPB     128          // edges per block in fused edge MLP
#define NB_SCAN 196
#define BN_EPS  1e-5f
#define STAT_BLOCKS 128

typedef __attribute__((ext_vector_type(8))) short s16x8;
typedef __attribute__((ext_vector_type(4))) float f32x4;

__device__ __forceinline__ unsigned short f2bf(float x) {
    unsigned u = __float_as_uint(x);
    return (unsigned short)((u + 0x7fffu + ((u >> 16) & 1u)) >> 16);
}
__device__ __forceinline__ float bf2f(unsigned short b) {
    return __uint_as_float(((unsigned)b) << 16);
}

// direct global->LDS 16B load (linear LDS dest = wave base + lane*16)
__device__ __forceinline__ void gload_lds16(const void* g, void* lds) {
    auto gp = reinterpret_cast<const __attribute__((address_space(1))) unsigned int*>(
        reinterpret_cast<uintptr_t>(g));
    auto lp = reinterpret_cast<__attribute__((address_space(3))) unsigned int*>(
        reinterpret_cast<uintptr_t>(lds));
    __builtin_amdgcn_global_load_lds(gp, lp, 16, 0, 0);
}

// ---------------- utility ----------------
__global__ void zero_i32(int* p, int n) {
    int i = blockIdx.x * blockDim.x + threadIdx.x;
    if (i < n) p[i] = 0;
}
__global__ void zero_f32(float* p, int n) {
    int i = blockIdx.x * blockDim.x + threadIdx.x;
    if (i < n) p[i] = 0.0f;
}
__global__ void count_deg(const int* __restrict__ dst, int* __restrict__ counts) {
    int e = blockIdx.x * blockDim.x + threadIdx.x;
    if (e < N_EDGES) atomicAdd(&counts[dst[e]], 1);
}
__global__ void isd_kernel(const int* __restrict__ counts, float* __restrict__ isd) {
    int i = blockIdx.x * blockDim.x + threadIdx.x;
    if (i < N_NODES) isd[i] = rsqrtf(1.0f + (float)counts[i]);
}

// ---------------- 3-phase scan ----------------
__global__ __launch_bounds__(256) void scan_reduce(const int* __restrict__ counts,
                                                   int* __restrict__ bsum) {
    __shared__ int sh[256];
    int t = threadIdx.x, b = blockIdx.x;
    int i = b * 256 + t;
    sh[t] = (i < N_NODES) ? counts[i] : 0;
    __syncthreads();
    for (int o = 128; o > 0; o >>= 1) {
        if (t < o) sh[t] += sh[t + o];
        __syncthreads();
    }
    if (t == 0) bsum[b] = sh[0];
}
__global__ __launch_bounds__(256) void scan_tops(const int* __restrict__ bsum,
                                                 int* __restrict__ boff, int nb,
                                                 int* __restrict__ total_out) {
    __shared__ int sh[256];
    int t = threadIdx.x;
    int v = (t < nb) ? bsum[t] : 0;
    sh[t] = v;
    __syncthreads();
    for (int o = 1; o < 256; o <<= 1) {
        int a = (t >= o) ? sh[t - o] : 0;
        __syncthreads();
        sh[t] += a;
        __syncthreads();
    }
    if (t < nb) boff[t] = sh[t] - v;
    if (t == 255) *total_out = sh[255];
}
__global__ __launch_bounds__(256) void scan_final(const int* __restrict__ counts,
                                                  const int* __restrict__ boff,
                                                  int* __restrict__ offsets) {
    __shared__ int sh[256];
    int t = threadIdx.x, b = blockIdx.x;
    int i = b * 256 + t;
    int v = (i < N_NODES) ? counts[i] : 0;
    sh[t] = v;
    __syncthreads();
    for (int o = 1; o < 256; o <<= 1) {
        int a = (t >= o) ? sh[t - o] : 0;
        __syncthreads();
        sh[t] += a;
        __syncthreads();
    }
    if (i < N_NODES) offsets[i] = boff[b] + sh[t] - v;
}

// packed CSR entry: (src, norm) as int2; also dst and orig-edge-id per CSR slot
__global__ void fill_csr(const int* __restrict__ src, const int* __restrict__ dst,
                         const float* __restrict__ isd, const int* __restrict__ offsets,
                         int* __restrict__ cursor, int2* __restrict__ pk,
                         int* __restrict__ edstA, int* __restrict__ eorigA) {
    int e = blockIdx.x * blockDim.x + threadIdx.x;
    if (e >= N_EDGES) return;
    int s = src[e], d = dst[e];
    int pos = offsets[d] + atomicAdd(&cursor[d], 1);
    pk[pos] = make_int2(s, __float_as_int(isd[s] * isd[d]));
    edstA[pos] = d;
    eorigA[pos] = e;
}

// ---------------- conversions ----------------
__global__ void conv_f32_bf16(const float* __restrict__ in, unsigned short* __restrict__ out,
                              int n4) {
    int i = blockIdx.x * blockDim.x + threadIdx.x;
    if (i >= n4) return;
    float4 v = ((const float4*)in)[i];
    unsigned short o0 = f2bf(v.x), o1 = f2bf(v.y), o2 = f2bf(v.z), o3 = f2bf(v.w);
    ((uint2*)out)[i] = make_uint2(((unsigned)o1 << 16) | o0, ((unsigned)o3 << 16) | o2);
}

__global__ void transp_conv(const float* __restrict__ W, unsigned short* __restrict__ Wt,
                            int K, int Nout) {
    int idx = blockIdx.x * blockDim.x + threadIdx.x;
    if (idx >= K * Nout) return;
    int k = idx / Nout, n = idx % Nout;
    Wt[(size_t)n * K + k] = f2bf(W[idx]);
}

// ---------------- bf16 MFMA GEMM (global_load_lds staging) ----------------
// C[M][Nout] = A[M][K] @ Wt[Nout][K]^T. OUT_MODE: 0=f32, 1=bf16.
// DUAL: grid.y=4, half=(y>>1) selects {A,Wt} vs {A2,Wt2}, output col offset half*256.
template <int BN_T, int OUT_MODE, int RELU, int BIAS, int DUAL>
__global__ __launch_bounds__(256) void gemm_mfma(const unsigned short* __restrict__ A, int lda,
                                                 const unsigned short* __restrict__ Wt,
                                                 const float* __restrict__ bias,
                                                 void* __restrict__ Cout, int ldc,
                                                 int M, int K,
                                                 const unsigned short* __restrict__ A2,
                                                 const unsigned short* __restrict__ Wt2) {
    constexpr int MI = (BN_T == 128) ? 4 : 2;
    constexpr int NI = 4;
    __shared__ __align__(16) short As[128 * 32];
    __shared__ __align__(16) short Bs[BN_T * 32];

    const int tid = threadIdx.x;
    const int l = tid & 63;
    const int wv = tid >> 6;
    const int wrow = (BN_T == 128) ? (wv >> 1) * 64 : wv * 32;
    const int wcol = (BN_T == 128) ? (wv & 1) * 64 : 0;
    const int bm = blockIdx.x * 128;
    int bn, coloff;
    const unsigned short* Ause;
    const unsigned short* Wuse;
    if (DUAL) {
        int half_ = blockIdx.y >> 1;
        bn = (blockIdx.y & 1) * BN_T;
        coloff = half_ * 256;
        Ause = half_ ? A2 : A;
        Wuse = half_ ? Wt2 : Wt;
    } else {
        bn = blockIdx.y * BN_T;
        coloff = 0;
        Ause = A;
        Wuse = Wt;
    }
    const int rsub = l >> 2;
    const int gl = l & 3;

    f32x4 acc[MI][NI] = {};

    for (int k0 = 0; k0 < K; k0 += 32) {
#pragma unroll
        for (int i = 0; i < 2; i++) {
            int lr = wv * 32 + i * 16 + rsub;
            int gr = bm + lr;
            if (gr >= M) gr = M - 1;
            int gsrc = gl ^ ((lr >> 1) & 3);
            gload_lds16(&Ause[(size_t)gr * lda + k0 + gsrc * 8],
                        &As[(wv * 32 + i * 16) * 32]);
        }
#pragma unroll
        for (int i = 0; i < BN_T / 64; i++) {
            int base = (BN_T == 128) ? (wv * 32 + i * 16) : (wv * 16);
            int lr = base + rsub;
            int gsrc = gl ^ ((lr >> 1) & 3);
            gload_lds16(&Wuse[(size_t)(bn + lr) * K + k0 + gsrc * 8],
                        &Bs[base * 32]);
        }
        __syncthreads();

        s16x8 af[MI], bfr[NI];
        const int q = l >> 4;
#pragma unroll
        for (int mi = 0; mi < MI; mi++) {
            int r = wrow + mi * 16 + (l & 15);
            af[mi] = *(const s16x8*)(&As[r * 32 + ((q ^ ((r >> 1) & 3)) << 3)]);
        }
#pragma unroll
        for (int ni = 0; ni < NI; ni++) {
            int r = wcol + ni * 16 + (l & 15);
            bfr[ni] = *(const s16x8*)(&Bs[r * 32 + ((q ^ ((r >> 1) & 3)) << 3)]);
        }
#pragma unroll
        for (int mi = 0; mi < MI; mi++)
#pragma unroll
            for (int ni = 0; ni < NI; ni++)
                acc[mi][ni] = __builtin_amdgcn_mfma_f32_16x16x32_bf16(af[mi], bfr[ni],
                                                                      acc[mi][ni], 0, 0, 0);
        __syncthreads();
    }

#pragma unroll
    for (int mi = 0; mi < MI; mi++) {
#pragma unroll
        for (int ni = 0; ni < NI; ni++) {
            int colB = coloff + bn + wcol + ni * 16 + (l & 15);
            float bv = BIAS ? bias[colB] : 0.0f;
#pragma unroll
            for (int r = 0; r < 4; r++) {
                int row = bm + wrow + mi * 16 + (l >> 4) * 4 + r;
                if (row < M) {
                    float v = acc[mi][ni][r] + bv;
                    if (RELU) v = fmaxf(v, 0.0f);
                    if (OUT_MODE == 1)
                        ((unsigned short*)Cout)[(size_t)row * ldc + colB] = f2bf(v);
                    else
                        ((float*)Cout)[(size_t)row * ldc + colB] = v;
                }
            }
        }
    }
}

// ---------------- fused edge MLP megakernel (512 threads, 8 waves) ----------------
// Per block: 128 CSR-ordered edges. Phase0: gather layer-1 into LDS A-tile.
// Then 3 chained GEMMs entirely in LDS, fused Wc5 output, scatter by eorig.
__global__ __launch_bounds__(512, 4) void edge_mlp_fused(
    const unsigned short* __restrict__ PQ, const int2* __restrict__ pk,
    const int* __restrict__ edstA, const int* __restrict__ eorigA,
    const float* __restrict__ ea, const float* __restrict__ Wc1e,
    const float* __restrict__ bc1,
    const unsigned short* __restrict__ Wc2t, const float* __restrict__ bc2,
    const unsigned short* __restrict__ Wc3t, const float* __restrict__ bc3,
    const unsigned short* __restrict__ Wc4t, const float* __restrict__ bc4,
    const float* __restrict__ Wc5, const float* __restrict__ bc5,
    float* __restrict__ out) {
    __shared__ __align__(16) short At[EPB * 256];  // 64KB, swizzled [row][ch]
    __shared__ __align__(16) short Bs[256 * 32];   // 16KB weight staging

    const int tid = threadIdx.x;
    const int l = tid & 63;
    const int wv = tid >> 6;           // 0..7
    const int p0 = blockIdx.x * EPB;
    const int lm = l & 15;
    const int q = l >> 4;
    const int rsub = l >> 2;
    const int gl = l & 3;

    // ---- phase 0: gather + edge layer 1 -> At (row=edge, ch=0..255) ----
    {
        const int c0 = l * 4;
        float bi0 = bc1[c0], bi1 = bc1[c0 + 1], bi2 = bc1[c0 + 2], bi3 = bc1[c0 + 3];
        float4 w8[8];
#pragma unroll
        for (int jj = 0; jj < 8; jj++) w8[jj] = *(const float4*)(&Wc1e[jj * 256 + c0]);
        const int g = l >> 1;
        const int sub = (l & 1) * 4;
#pragma unroll 4
        for (int i = 0; i < 16; i++) {
            int row = wv * 16 + i;
            int p = p0 + row;
            int s = pk[p].x;
            int d = edstA[p];
            int eo = eorigA[p];
            union { int2 v; unsigned short u[4]; } Pu, Qu;
            Pu.v = *(const int2*)(&PQ[(size_t)s * 512 + c0]);
            Qu.v = *(const int2*)(&PQ[(size_t)d * 512 + 256 + c0]);
            float v0 = bf2f(Pu.u[0]) + bf2f(Qu.u[0]) + bi0;
            float v1 = bf2f(Pu.u[1]) + bf2f(Qu.u[1]) + bi1;
            float v2 = bf2f(Pu.u[2]) + bf2f(Qu.u[2]) + bi2;
            float v3 = bf2f(Pu.u[3]) + bf2f(Qu.u[3]) + bi3;
#pragma unroll
            for (int jj = 0; jj < 8; jj++) {
                float av = ea[(size_t)eo * 8 + jj];
                v0 = fmaf(av, w8[jj].x, v0);
                v1 = fmaf(av, w8[jj].y, v1);
                v2 = fmaf(av, w8[jj].z, v2);
                v3 = fmaf(av, w8[jj].w, v3);
            }
            unsigned short o0 = f2bf(fmaxf(v0, 0.0f)), o1 = f2bf(fmaxf(v1, 0.0f));
            unsigned short o2 = f2bf(fmaxf(v2, 0.0f)), o3 = f2bf(fmaxf(v3, 0.0f));
            int off = row * 256 + ((g ^ (row & 7)) << 3) + sub;
            *(uint2*)(&At[off]) =
                make_uint2(((unsigned)o1 << 16) | o0, ((unsigned)o3 << 16) | o2);
        }
    }
    __syncthreads();

    // ---- GEMM1: [128x256] = relu(At @ Wc2t^T + bc2) -> At ----
    {
        const int wrow = (wv >> 2) * 64;   // 0,64
        const int wcol = (wv & 3) * 64;    // 0,64,128,192
        f32x4 acc[4][4] = {};
        for (int k0 = 0; k0 < 256; k0 += 32) {
#pragma unroll
            for (int i = 0; i < 2; i++) {
                int lr = wv * 32 + i * 16 + rsub;
                int gsrc = gl ^ ((lr >> 1) & 3);
                gload_lds16(&Wc2t[(size_t)lr * 256 + k0 + gsrc * 8],
                            &Bs[(wv * 32 + i * 16) * 32]);
            }
            __syncthreads();
            s16x8 af[4], bfr[4];
#pragma unroll
            for (int mi = 0; mi < 4; mi++) {
                int r = wrow + mi * 16 + lm;
                int G = (k0 >> 3) + q;
                af[mi] = *(const s16x8*)(&At[r * 256 + ((G ^ (r & 7)) << 3)]);
            }
#pragma unroll
            for (int ni = 0; ni < 4; ni++) {
                int rb = wcol + ni * 16 + lm;
                bfr[ni] = *(const s16x8*)(&Bs[rb * 32 + ((q ^ ((rb >> 1) & 3)) << 3)]);
            }
#pragma unroll
            for (int mi = 0; mi < 4; mi++)
#pragma unroll
                for (int ni = 0; ni < 4; ni++)
                    acc[mi][ni] = __builtin_amdgcn_mfma_f32_16x16x32_bf16(
                        af[mi], bfr[ni], acc[mi][ni], 0, 0, 0);
            __syncthreads();
        }
        // epilogue back into At (all reads complete after final barrier)
#pragma unroll
        for (int mi = 0; mi < 4; mi++) {
#pragma unroll
            for (int ni = 0; ni < 4; ni++) {
                int col = wcol + ni * 16 + lm;
                float bv = bc2[col];
#pragma unroll
                for (int r = 0; r < 4; r++) {
                    int row = wrow + mi * 16 + q * 4 + r;
                    At[row * 256 + (((col >> 3) ^ (row & 7)) << 3) + (col & 7)] =
                        (short)f2bf(fmaxf(acc[mi][ni][r] + bv, 0.0f));
                }
            }
        }
    }
    __syncthreads();

    // ---- GEMM2: [128x128] = relu(A2 @ Wc3t^T + bc3) -> At (stride 128) ----
    {
        const int wrow = (wv >> 1) * 32;   // 0,32,64,96
        const int wcol = (wv & 1) * 64;    // 0,64
        f32x4 acc[2][4] = {};
        for (int k0 = 0; k0 < 256; k0 += 32) {
            {
                int lr = wv * 16 + rsub;
                int gsrc = gl ^ ((lr >> 1) & 3);
                gload_lds16(&Wc3t[(size_t)lr * 256 + k0 + gsrc * 8],
                            &Bs[(wv * 16) * 32]);
            }
            __syncthreads();
            s16x8 af[2], bfr[4];
#pragma unroll
            for (int mi = 0; mi < 2; mi++) {
                int r = wrow + mi * 16 + lm;
                int G = (k0 >> 3) + q;
                af[mi] = *(const s16x8*)(&At[r * 256 + ((G ^ (r & 7)) << 3)]);
            }
#pragma unroll
            for (int ni = 0; ni < 4; ni++) {
                int rb = wcol + ni * 16 + lm;
                bfr[ni] = *(const s16x8*)(&Bs[rb * 32 + ((q ^ ((rb >> 1) & 3)) << 3)]);
            }
#pragma unroll
            for (int mi = 0; mi < 2; mi++)
#pragma unroll
                for (int ni = 0; ni < 4; ni++)
                    acc[mi][ni] = __builtin_amdgcn_mfma_f32_16x16x32_bf16(
                        af[mi], bfr[ni], acc[mi][ni], 0, 0, 0);
            __syncthreads();
        }
#pragma unroll
        for (int mi = 0; mi < 2; mi++) {
#pragma unroll
            for (int ni = 0; ni < 4; ni++) {
                int col = wcol + ni * 16 + lm;
                float bv = bc3[col];
#pragma unroll
                for (int r = 0; r < 4; r++) {
                    int row = wrow + mi * 16 + q * 4 + r;
                    At[row * 128 + (((col >> 3) ^ (row & 7)) << 3) + (col & 7)] =
                        (short)f2bf(fmaxf(acc[mi][ni][r] + bv, 0.0f));
                }
            }
        }
    }
    __syncthreads();

    // ---- GEMM3: [128x64] = A3 @ Wc4t^T, fused relu+bc4 then @Wc5 + bc5, scatter ----
    {
        const int wrow = wv * 16;
        f32x4 acc[4] = {};
        for (int k0 = 0; k0 < 128; k0 += 32) {
            if (wv < 4) {
                int lr = wv * 16 + rsub;
                int gsrc = gl ^ ((lr >> 1) & 3);
                gload_lds16(&Wc4t[(size_t)lr * 128 + k0 + gsrc * 8],
                            &Bs[(wv * 16) * 32]);
            }
            __syncthreads();
            s16x8 af, bfr[4];
            {
                int r = wrow + lm;
                int G = (k0 >> 3) + q;
                af = *(const s16x8*)(&At[r * 128 + ((G ^ (r & 7)) << 3)]);
            }
#pragma unroll
            for (int ni = 0; ni < 4; ni++) {
                int rb = ni * 16 + lm;
                bfr[ni] = *(const s16x8*)(&Bs[rb * 32 + ((q ^ ((rb >> 1) & 3)) << 3)]);
            }
#pragma unroll
            for (int ni = 0; ni < 4; ni++)
                acc[ni] = __builtin_amdgcn_mfma_f32_16x16x32_bf16(af, bfr[ni],
                                                                  acc[ni], 0, 0, 0);
            __syncthreads();
        }
#pragma unroll
        for (int r = 0; r < 4; r++) {
            float pa = 0.f, pb = 0.f;
#pragma unroll
            for (int ni = 0; ni < 4; ni++) {
                int col = ni * 16 + lm;
                float v = fmaxf(acc[ni][r] + bc4[col], 0.0f);
                pa = fmaf(v, Wc5[col * 2 + 0], pa);
                pb = fmaf(v, Wc5[col * 2 + 1], pb);
            }
#pragma unroll
            for (int o = 1; o < 16; o <<= 1) {
                pa += __shfl_xor(pa, o, 64);
                pb += __shfl_xor(pb, o, 64);
            }
            if (lm == 0) {
                int row = wrow + q * 4 + r;
                int eo = eorigA[p0 + row];
                out[(size_t)eo * 2 + 0] = pa + bc5[0];
                out[(size_t)eo * 2 + 1] = pb + bc5[1];
            }
        }
    }
}

// ---------------- GCN aggregation: 1 node/wave, packed pairs, bf16 out ----------------
__global__ __launch_bounds__(256) void aggregate2(const unsigned short* __restrict__ hwb,
                                                  const float* __restrict__ isd,
                                                  const int* __restrict__ offsets,
                                                  const int2* __restrict__ pk,
                                                  const float* __restrict__ b1,
                                                  const float* __restrict__ b2,
                                                  unsigned short* __restrict__ hagg) {
    int wv = threadIdx.x >> 6, l = threadIdx.x & 63;
    int n = blockIdx.x * 4 + wv;
    int c0 = l * 8;
    float acc[8] = {};
    int e0 = offsets[n], e1 = offsets[n + 1];
    int k = e0;
    for (; k + 2 <= e1; k += 2) {
        int2 p0 = pk[k], p1 = pk[k + 1];
        union { int4 v; unsigned short u[8]; } U0, U1;
        U0.v = *(const int4*)(&hwb[(size_t)p0.x * 512 + c0]);
        U1.v = *(const int4*)(&hwb[(size_t)p1.x * 512 + c0]);
        float w0 = __int_as_float(p0.y), w1 = __int_as_float(p1.y);
#pragma unroll
        for (int j = 0; j < 8; j++)
            acc[j] = fmaf(w0, bf2f(U0.u[j]), fmaf(w1, bf2f(U1.u[j]), acc[j]));
    }
    if (k < e1) {
        int2 p0 = pk[k];
        union { int4 v; unsigned short u[8]; } U0;
        U0.v = *(const int4*)(&hwb[(size_t)p0.x * 512 + c0]);
        float w0 = __int_as_float(p0.y);
#pragma unroll
        for (int j = 0; j < 8; j++) acc[j] = fmaf(w0, bf2f(U0.u[j]), acc[j]);
    }
    float si = isd[n]; si *= si;
    union { int4 v; unsigned short u[8]; } U;
    U.v = *(const int4*)(&hwb[(size_t)n * 512 + c0]);
    const float* bp = (c0 < 256) ? (b1 + c0) : (b2 + (c0 - 256));
    unsigned short os[8];
#pragma unroll
    for (int j = 0; j < 8; j++) {
        acc[j] = fmaf(si, bf2f(U.u[j]), acc[j]) + bp[j];
        os[j] = f2bf(acc[j]);
    }
    int4 ov;
    ov.x = (int)(((unsigned)os[1] << 16) | os[0]);
    ov.y = (int)(((unsigned)os[3] << 16) | os[2]);
    ov.z = (int)(((unsigned)os[5] << 16) | os[4]);
    ov.w = (int)(((unsigned)os[7] << 16) | os[6]);
    *(int4*)(&hagg[(size_t)n * 512 + c0]) = ov;
}

// ---------------- BN stats over bf16 [N][512] ----------------
__global__ __launch_bounds__(256) void bn_stats2(const unsigned short* __restrict__ h,
                                                 float* __restrict__ stats) {
    __shared__ float sh[4][1024];
    int t = threadIdx.x;
    int wv = t >> 6, l = t & 63;
    int c0 = l * 8;
    float s[8] = {}, q[8] = {};
    for (int n = blockIdx.x * 4 + wv; n < N_NODES; n += STAT_BLOCKS * 4) {
        union { int4 v; unsigned short u[8]; } U;
        U.v = *(const int4*)(&h[(size_t)n * 512 + c0]);
#pragma unroll
        for (int j = 0; j < 8; j++) {
            float x = bf2f(U.u[j]);
            s[j] += x;
            q[j] = fmaf(x, x, q[j]);
        }
    }
#pragma unroll
    for (int j = 0; j < 8; j++) {
        sh[wv][c0 + j] = s[j];
        sh[wv][512 + c0 + j] = q[j];
    }
    __syncthreads();
    for (int i = t; i < 1024; i += 256) {
        float a = sh[0][i] + sh[1][i] + sh[2][i] + sh[3][i];
        atomicAdd(&stats[i], a);
    }
}

// stats -> per-channel affine AB: y = x*AB[c] + AB[512+c]
__global__ __launch_bounds__(256) void bn_ab(const float* __restrict__ stats,
                                             const float* __restrict__ g,
                                             const float* __restrict__ be,
                                             float* __restrict__ AB) {
    int t = threadIdx.x;
#pragma unroll
    for (int h = 0; h < 2; h++) {
        int c = t + h * 256;
        float m = stats[c] * (1.0f / N_NODES);
        float var = stats[512 + c] * (1.0f / N_NODES) - m * m;
        float sc = g[c & 255] * rsqrtf(var + BN_EPS);
        AB[c] = sc;
        AB[512 + c] = be[c & 255] - m * sc;
    }
}

// y = relu(x*A + B), bf16 in/out, 512-wide
__global__ __launch_bounds__(256) void bn_apply(const unsigned short* __restrict__ h,
                                                const float* __restrict__ AB,
                                                unsigned short* __restrict__ outp) {
    int i8 = blockIdx.x * blockDim.x + threadIdx.x;
    if (i8 >= N_NODES * 512 / 8) return;
    int c8 = (i8 & 63) * 8;
    union { int4 v; unsigned short u[8]; } U;
    U.v = *(const int4*)(&h[(size_t)i8 * 8]);
    unsigned short os[8];
#pragma unroll
    for (int j = 0; j < 8; j++) {
        int c = c8 + j;
        float y = fmaf(bf2f(U.u[j]), AB[c], AB[512 + c]);
        os[j] = f2bf(fmaxf(y, 0.0f));
    }
    int4 ov;
    ov.x = (int)(((unsigned)os[1] << 16) | os[0]);
    ov.y = (int)(((unsigned)os[3] << 16) | os[2]);
    ov.z = (int)(((unsigned)os[5] << 16) | os[4]);
    ov.w = (int)(((unsigned)os[7] << 16) | os[6]);
    *(int4*)(&outp[(size_t)i8 * 8]) = ov;
}

// final: hc = relu(bn(h1)) + relu(bn(h2)), bf16 out 256-wide
__global__ __launch_bounds__(256) void bn_apply_final(const unsigned short* __restrict__ h,
                                                      const float* __restrict__ AB,
                                                      unsigned short* __restrict__ hc) {
    int i8 = blockIdx.x * blockDim.x + threadIdx.x;
    if (i8 >= N_NODES * 256 / 8) return;
    int n = i8 >> 5;
    int c8 = (i8 & 31) * 8;
    union { int4 v; unsigned short u[8]; } U1, U2;
    U1.v = *(const int4*)(&h[(size_t)n * 512 + c8]);
    U2.v = *(const int4*)(&h[(size_t)n * 512 + 256 + c8]);
    unsigned short os[8];
#pragma unroll
    for (int j = 0; j < 8; j++) {
        int c = c8 + j;
        float y1 = fmaxf(fmaf(bf2f(U1.u[j]), AB[c], AB[512 + c]), 0.0f);
        int c2 = c + 256;
        float y2 = fmaxf(fmaf(bf2f(U2.u[j]), AB[c2], AB[512 + c2]), 0.0f);
        os[j] = f2bf(y1 + y2);
    }
    int4 ov;
    ov.x = (int)(((unsigned)os[1] << 16) | os[0]);
    ov.y = (int)(((unsigned)os[3] << 16) | os[2]);
    ov.z = (int)(((unsigned)os[5] << 16) | os[4]);
    ov.w = (int)(((unsigned)os[7] << 16) | os[6]);
    *(int4*)(&hc[(size_t)i8 * 8]) = ov;
}

// ---------------- launch ----------------
extern "C" void kernel_launch(void* const* d_in, const int* in_sizes, int n_in,
                              void* d_out, int out_size, void* d_ws, size_t ws_size,
                              hipStream_t stream) {
    const float* x   = (const float*)d_in[0];
    const int*   ei  = (const int*)d_in[1];
    const float* ea  = (const float*)d_in[2];
    const float* W11 = (const float*)d_in[3];
    const float* b11 = (const float*)d_in[4];
    const float* W12 = (const float*)d_in[5];
    const float* b12 = (const float*)d_in[6];
    const float* W13 = (const float*)d_in[7];
    const float* b13 = (const float*)d_in[8];
    const float* W21 = (const float*)d_in[9];
    const float* b21 = (const float*)d_in[10];
    const float* W22 = (const float*)d_in[11];
    const float* b22 = (const float*)d_in[12];
    const float* W23 = (const float*)d_in[13];
    const float* b23 = (const float*)d_in[14];
    const float* g1  = (const float*)d_in[15];
    const float* be1 = (const float*)d_in[16];
    const float* g2  = (const float*)d_in[17];
    const float* be2 = (const float*)d_in[18];
    const float* g3  = (const float*)d_in[19];
    const float* be3 = (const float*)d_in[20];
    const float* Wc1 = (const float*)d_in[21];
    const float* bc1 = (const float*)d_in[22];
    const float* Wc2 = (const float*)d_in[23];
    const float* bc2 = (const float*)d_in[24];
    const float* Wc3 = (const float*)d_in[25];
    const float* bc3 = (const float*)d_in[26];
    const float* Wc4 = (const float*)d_in[27];
    const float* bc4 = (const float*)d_in[28];
    const float* Wc5 = (const float*)d_in[29];
    const float* bc5 = (const float*)d_in[30];

    const int* src = ei;
    const int* dst = ei + N_EDGES;
    float* out = (float*)d_out;

    // ---- workspace carve ----
    char* w = (char*)d_ws;
    auto alloc = [&](size_t bytes) {
        char* p = w;
        w += (bytes + 255) & ~(size_t)255;
        return p;
    };
    float* isd     = (float*)alloc(N_NODES * 4);
    int2*  pk      = (int2*)alloc((size_t)N_EDGES * 8);
    int*   edstA   = (int*)alloc((size_t)N_EDGES * 4);
    int*   eorigA  = (int*)alloc((size_t)N_EDGES * 4);
    int*   counts  = (int*)alloc((N_NODES + 4) * 4);
    int*   offsets = (int*)alloc((N_NODES + 4) * 4);
    int*   bsum    = (int*)alloc(256 * 4);
    int*   boff    = (int*)alloc(256 * 4);
    float* stats   = (float*)alloc(1024 * 4);
    float* AB      = (float*)alloc(1024 * 4);
    unsigned short* W11t = (unsigned short*)alloc(256 * 128 * 2);
    unsigned short* W21t = (unsigned short*)alloc(256 * 128 * 2);
    unsigned short* W12t = (unsigned short*)alloc(256 * 256 * 2);
    unsigned short* W22t = (unsigned short*)alloc(256 * 256 * 2);
    unsigned short* W13t = (unsigned short*)alloc(256 * 256 * 2);
    unsigned short* W23t = (unsigned short*)alloc(256 * 256 * 2);
    unsigned short* WPQt = (unsigned short*)alloc(512 * 256 * 2);
    unsigned short* Wc2t = (unsigned short*)alloc(256 * 256 * 2);
    unsigned short* Wc3t = (unsigned short*)alloc(128 * 256 * 2);
    unsigned short* Wc4t = (unsigned short*)alloc(64 * 128 * 2);
    unsigned short* xb   = (unsigned short*)alloc((size_t)N_NODES * 128 * 2);
    unsigned short* hb   = (unsigned short*)alloc((size_t)N_NODES * 512 * 2);
    unsigned short* hwb  = (unsigned short*)alloc((size_t)N_NODES * 512 * 2);
    unsigned short* hagg = (unsigned short*)alloc((size_t)N_NODES * 512 * 2);
    unsigned short* hc   = (unsigned short*)alloc((size_t)N_NODES * 256 * 2);
    (void)ws_size;

    // ---- CSR build ----
    zero_i32<<<(N_NODES + 256) / 256, 256, 0, stream>>>(counts, N_NODES + 1);
    count_deg<<<(N_EDGES + 255) / 256, 256, 0, stream>>>(dst, counts);
    isd_kernel<<<(N_NODES + 255) / 256, 256, 0, stream>>>(counts, isd);
    scan_reduce<<<NB_SCAN, 256, 0, stream>>>(counts, bsum);
    scan_tops<<<1, 256, 0, stream>>>(bsum, boff, NB_SCAN, offsets + N_NODES);
    scan_final<<<NB_SCAN, 256, 0, stream>>>(counts, boff, offsets);
    zero_i32<<<(N_NODES + 255) / 256, 256, 0, stream>>>(counts, N_NODES);
    fill_csr<<<(N_EDGES + 255) / 256, 256, 0, stream>>>(src, dst, isd, offsets, counts,
                                                        pk, edstA, eorigA);

    // ---- preconvert ----
    conv_f32_bf16<<<(N_NODES * 128 / 4 + 255) / 256, 256, 0, stream>>>(x, xb,
                                                                        N_NODES * 128 / 4);
    auto tr = [&](const float* W, unsigned short* Wt, int K, int Nout) {
        transp_conv<<<(K * Nout + 255) / 256, 256, 0, stream>>>(W, Wt, K, Nout);
    };
    tr(W11, W11t, 128, 256); tr(W21, W21t, 128, 256);
    tr(W12, W12t, 256, 256); tr(W22, W22t, 256, 256);
    tr(W13, W13t, 256, 256); tr(W23, W23t, 256, 256);
    tr(Wc1, WPQt, 256, 256);
    tr(Wc1 + 256 * 256, WPQt + 256 * 256, 256, 256);
    tr(Wc2, Wc2t, 256, 256);
    tr(Wc3, Wc3t, 256, 128);
    tr(Wc4, Wc4t, 128, 64);

    // ---- 3 GCN layers (dual-branch GEMM in one dispatch) ----
    const unsigned short* Wat[3] = {W11t, W12t, W13t};
    const unsigned short* Wbt[3] = {W21t, W22t, W23t};
    const float* ba[3] = {b11, b12, b13};
    const float* bb[3] = {b21, b22, b23};
    const float* gs[3] = {g1, g2, g3};
    const float* bes[3] = {be1, be2, be3};

    int gx_n = (N_NODES + 127) / 128;  // 391
    for (int l = 0; l < 3; l++) {
        if (l == 0) {
            gemm_mfma<128, 1, 0, 0, 1><<<dim3(gx_n, 4), 256, 0, stream>>>(
                xb, 128, Wat[0], nullptr, hwb, 512, N_NODES, 128, xb, Wbt[0]);
        } else {
            gemm_mfma<128, 1, 0, 0, 1><<<dim3(gx_n, 4), 256, 0, stream>>>(
                hb, 512, Wat[l], nullptr, hwb, 512, N_NODES, 256, hb + 256, Wbt[l]);
        }
        aggregate2<<<N_NODES / 4, 256, 0, stream>>>(hwb, isd, offsets, pk,
                                                    ba[l], bb[l], hagg);
        zero_f32<<<4, 256, 0, stream>>>(stats, 1024);
        bn_stats2<<<STAT_BLOCKS, 256, 0, stream>>>(hagg, stats);
        bn_ab<<<1, 256, 0, stream>>>(stats, gs[l], bes[l], AB);
        if (l < 2) {
            bn_apply<<<(N_NODES * 512 / 8 + 255) / 256, 256, 0, stream>>>(hagg, AB, hb);
        } else {
            bn_apply_final<<<(N_NODES * 256 / 8 + 255) / 256, 256, 0, stream>>>(hagg, AB, hc);
        }
    }

    // ---- PQ = hc @ [Wc1_P | Wc1_Q] -> hwb [N][512] bf16 ----
    gemm_mfma<128, 1, 0, 0, 0><<<dim3(gx_n, 4), 256, 0, stream>>>(hc, 256, WPQt, nullptr,
                                                                  hwb, 512, N_NODES, 256,
                                                                  nullptr, nullptr);

    // ---- fused edge MLP: one dispatch, all 400K edges ----
    edge_mlp_fused<<<N_EDGES / EPB, 512, 0, stream>>>(
        hwb, pk, edstA, eorigA, ea, Wc1 + 512 * 256, bc1,
        Wc2t, bc2, Wc3t, bc3, Wc4t, bc4, Wc5, bc5, out);
}